// Round 2
// baseline (6181.642 us; speedup 1.0000x reference)
//
#include <hip/hip_runtime.h>
#include <hip/hip_bf16.h>
#include <hip/hip_fp16.h>

#define NN 100000
#define NE 1600000
#define HEADS 4
#define EM 64
#define HF 256      // HEADS*EM
#define IN_DIM 128
#define HI 64
#define OUT_DIM 128

__device__ __forceinline__ float lrelu(float x) { return x > 0.f ? x : 0.01f * x; }

struct H4 { __half2 a, b; };   // 4 fp16 = 8 bytes

// ---------------- Kernel 1: per-head node MLP + attention projections ----------------
// hs[n][h*64+k]   = (leaky(x[n]·Wi1[h] + bi1)·Wi2[h] + bi2)          (stored fp16)
// ssrc[n][h*64+k] = hs[n][h]·Wa1[h][:64]                              (stored fp16)
// sdst[n][h*64+k] = hs[n][h]·Wa1[h][64:]                              (stored fp16)
#define NPB 8
__global__ __launch_bounds__(256) void k_node_embed(
    const float* __restrict__ x,
    const float* __restrict__ Wi1, const float* __restrict__ bi1,
    const float* __restrict__ Wi2, const float* __restrict__ bi2,
    const float* __restrict__ Wa1,
    __half* __restrict__ hs, __half* __restrict__ ssrc, __half* __restrict__ sdst)
{
    __shared__ float xs[NPB][IN_DIM];
    __shared__ float h1s[NPB][HF];
    __shared__ float hss[NPB][HF];
    const int t = threadIdx.x;
    const int nbase = blockIdx.x * NPB;

    // stage x rows (8 nodes x 128 f32 = 4KB)
    {
        int i = t >> 5;             // node 0..7
        int f = (t & 31) << 2;      // 0..124
        float4 v = *(const float4*)(x + (size_t)(nbase + i) * IN_DIM + f);
        xs[i][f] = v.x; xs[i][f + 1] = v.y; xs[i][f + 2] = v.z; xs[i][f + 3] = v.w;
    }
    __syncthreads();

    const int h = t >> 6, k = t & 63;
    float acc[NPB];

    // layer 1: 128 -> 64 per head
    {
        const float* w = Wi1 + (size_t)h * IN_DIM * EM + k;
        #pragma unroll
        for (int i = 0; i < NPB; ++i) acc[i] = 0.f;
        for (int f = 0; f < IN_DIM; ++f) {
            float wv = w[f * EM];
            #pragma unroll
            for (int i = 0; i < NPB; ++i) acc[i] = fmaf(xs[i][f], wv, acc[i]);
        }
        float b = bi1[h * EM + k];
        #pragma unroll
        for (int i = 0; i < NPB; ++i) h1s[i][t] = lrelu(acc[i] + b);
    }
    __syncthreads();

    // layer 2: 64 -> 64 per head
    {
        const float* w = Wi2 + (size_t)h * EM * EM + k;
        #pragma unroll
        for (int i = 0; i < NPB; ++i) acc[i] = 0.f;
        for (int f = 0; f < EM; ++f) {
            float wv = w[f * EM];
            #pragma unroll
            for (int i = 0; i < NPB; ++i) acc[i] = fmaf(h1s[i][h * EM + f], wv, acc[i]);
        }
        float b = bi2[h * EM + k];
        #pragma unroll
        for (int i = 0; i < NPB; ++i) {
            float v = acc[i] + b;
            hss[i][t] = v;
            hs[(size_t)(nbase + i) * HF + t] = __float2half_rn(v);
        }
    }
    __syncthreads();

    // attention projections: s_src / s_dst (64 -> 64 each, per head)
    {
        const float* w = Wa1 + (size_t)h * (2 * EM) * HI + k;
        float accs[NPB], accd[NPB];
        #pragma unroll
        for (int i = 0; i < NPB; ++i) { accs[i] = 0.f; accd[i] = 0.f; }
        for (int f = 0; f < EM; ++f) {
            float wsv = w[f * HI];
            float wdv = w[(EM + f) * HI];
            #pragma unroll
            for (int i = 0; i < NPB; ++i) {
                float hv = hss[i][h * EM + f];
                accs[i] = fmaf(hv, wsv, accs[i]);
                accd[i] = fmaf(hv, wdv, accd[i]);
            }
        }
        #pragma unroll
        for (int i = 0; i < NPB; ++i) {
            ssrc[(size_t)(nbase + i) * HF + t] = __float2half_rn(accs[i]);
            sdst[(size_t)(nbase + i) * HF + t] = __float2half_rn(accd[i]);
        }
    }
}

// ---------------- Kernel 2: per-edge attention logits + exp + softmax denom ----------------
// one 64-lane wave per edge; lane l covers features 4l..4l+3 of the 256-wide row
__global__ __launch_bounds__(256) void k_edge_att(
    const int* __restrict__ ei,
    const __half* __restrict__ ssrc, const __half* __restrict__ sdst,
    const float* __restrict__ ba1, const float* __restrict__ Wa2, const float* __restrict__ ba2,
    float* __restrict__ eatt, float* __restrict__ esum)
{
    const int wave = threadIdx.x >> 6;
    const int lane = threadIdx.x & 63;
    const int e = blockIdx.x * 4 + wave;
    if (e >= NE) return;
    const int src = ei[e];
    const int dst = ei[NE + e];
    const int h = lane >> 4;        // head
    const int kq = lane & 15;       // 4-elem group within head
    const int kb = h * EM + kq * 4; // feature base

    H4 vs = ((const H4*)(ssrc + (size_t)src * HF))[lane];
    H4 vd = ((const H4*)(sdst + (size_t)dst * HF))[lane];
    float2 s0 = __half22float2(vs.a), s1 = __half22float2(vs.b);
    float2 d0 = __half22float2(vd.a), d1 = __half22float2(vd.b);

    float t0 = lrelu(s0.x + d0.x + ba1[kb + 0]);
    float t1 = lrelu(s0.y + d0.y + ba1[kb + 1]);
    float t2 = lrelu(s1.x + d1.x + ba1[kb + 2]);
    float t3 = lrelu(s1.y + d1.y + ba1[kb + 3]);

    const float* w2 = Wa2 + h * EM + kq * 4;
    float p = t0 * w2[0] + t1 * w2[1] + t2 * w2[2] + t3 * w2[3];
    p += __shfl_xor(p, 1);
    p += __shfl_xor(p, 2);
    p += __shfl_xor(p, 4);
    p += __shfl_xor(p, 8);

    if (kq == 0) {
        float a = lrelu(p + ba2[h]);
        float eh = expf(a);
        eatt[(size_t)e * HEADS + h] = eh;
        unsafeAtomicAdd(esum + (size_t)src * HEADS + h, eh);
    }
}

// ---------------- Kernel 3: alpha = e/esum[src]; scatter-add hs[src]*alpha onto agg[dst] ----------------
__global__ __launch_bounds__(256) void k_aggregate(
    const int* __restrict__ ei,
    const __half* __restrict__ hs,
    const float* __restrict__ eatt, const float* __restrict__ esum,
    float* __restrict__ agg)
{
    const int wave = threadIdx.x >> 6;
    const int lane = threadIdx.x & 63;
    const int e = blockIdx.x * 4 + wave;
    if (e >= NE) return;
    const int src = ei[e];
    const int dst = ei[NE + e];
    const int h = lane >> 4;

    float alpha = eatt[(size_t)e * HEADS + h] / esum[(size_t)src * HEADS + h];
    H4 hv = ((const H4*)(hs + (size_t)src * HF))[lane];
    float2 h0 = __half22float2(hv.a), h1 = __half22float2(hv.b);
    float* d = agg + (size_t)dst * HF + lane * 4;
    unsafeAtomicAdd(d + 0, h0.x * alpha);
    unsafeAtomicAdd(d + 1, h0.y * alpha);
    unsafeAtomicAdd(d + 2, h1.x * alpha);
    unsafeAtomicAdd(d + 3, h1.y * alpha);
}

// ---------------- Kernel 4: output MLP 256 -> 64 (leaky) -> 128 ----------------
__global__ __launch_bounds__(256) void k_out_mlp(
    const float* __restrict__ agg,
    const float* __restrict__ Wf1, const float* __restrict__ bf1,
    const float* __restrict__ Wf2, const float* __restrict__ bf2,
    float* __restrict__ out)
{
    __shared__ float aggL[NPB][HF];
    __shared__ float midL[NPB][HI];
    const int t = threadIdx.x;
    const int nbase = blockIdx.x * NPB;

    {
        int i = t >> 5;             // node 0..7
        int f = (t & 31) << 3;      // 0..248 step 8
        const float4* p = (const float4*)(agg + (size_t)(nbase + i) * HF + f);
        float4 a = p[0], b = p[1];
        aggL[i][f + 0] = a.x; aggL[i][f + 1] = a.y; aggL[i][f + 2] = a.z; aggL[i][f + 3] = a.w;
        aggL[i][f + 4] = b.x; aggL[i][f + 5] = b.y; aggL[i][f + 6] = b.z; aggL[i][f + 7] = b.w;
    }
    __syncthreads();

    // 256 -> 64, each thread does 2 nodes
    {
        int k = t & 63, g = t >> 6;     // g 0..3
        float a0 = 0.f, a1 = 0.f;
        for (int f = 0; f < HF; ++f) {
            float w = Wf1[f * HI + k];
            a0 = fmaf(aggL[g][f], w, a0);
            a1 = fmaf(aggL[g + 4][f], w, a1);
        }
        float b = bf1[k];
        midL[g][k] = lrelu(a0 + b);
        midL[g + 4][k] = lrelu(a1 + b);
    }
    __syncthreads();

    // 64 -> 128, each thread does 4 nodes
    {
        int o = t & 127, g2 = t >> 7;   // g2 0..1
        float c0 = 0.f, c1 = 0.f, c2 = 0.f, c3 = 0.f;
        for (int f = 0; f < HI; ++f) {
            float w = Wf2[f * OUT_DIM + o];
            c0 = fmaf(midL[g2 + 0][f], w, c0);
            c1 = fmaf(midL[g2 + 2][f], w, c1);
            c2 = fmaf(midL[g2 + 4][f], w, c2);
            c3 = fmaf(midL[g2 + 6][f], w, c3);
        }
        float b = bf2[o];
        out[(size_t)(nbase + g2 + 0) * OUT_DIM + o] = c0 + b;
        out[(size_t)(nbase + g2 + 2) * OUT_DIM + o] = c1 + b;
        out[(size_t)(nbase + g2 + 4) * OUT_DIM + o] = c2 + b;
        out[(size_t)(nbase + g2 + 6) * OUT_DIM + o] = c3 + b;
    }
}

extern "C" void kernel_launch(void* const* d_in, const int* in_sizes, int n_in,
                              void* d_out, int out_size, void* d_ws, size_t ws_size,
                              hipStream_t stream) {
    const float* x   = (const float*)d_in[0];
    const int*   ei  = (const int*)d_in[1];
    const float* Wi1 = (const float*)d_in[2];
    const float* bi1 = (const float*)d_in[3];
    const float* Wi2 = (const float*)d_in[4];
    const float* bi2 = (const float*)d_in[5];
    const float* Wa1 = (const float*)d_in[6];
    const float* ba1 = (const float*)d_in[7];
    const float* Wa2 = (const float*)d_in[8];
    const float* ba2 = (const float*)d_in[9];
    const float* Wf1 = (const float*)d_in[10];
    const float* bf1 = (const float*)d_in[11];
    const float* Wf2 = (const float*)d_in[12];
    const float* bf2 = (const float*)d_in[13];
    float* out = (float*)d_out;

    // workspace layout (compact, fp16 node arrays):
    //   [0, 51.2MB)        hs    (half,  NN*HF)
    //   [51.2, 102.4MB)    ssrc  (half)   } aliased by agg (float, NN*HF = 102.4MB)
    //   [102.4, 153.6MB)   sdst  (half)   }   after K2 completes
    //   [153.6, 179.2MB)   eatt  (float, NE*HEADS)
    //   [179.2, 180.8MB)   esum  (float, NN*HEADS)
    const size_t HS_B = (size_t)NN * HF * sizeof(__half);   // 51.2e6
    const size_t EATT_B = (size_t)NE * HEADS * sizeof(float); // 25.6e6
    const size_t ESUM_B = (size_t)NN * HEADS * sizeof(float); // 1.6e6
    const size_t NEED = 3 * HS_B + EATT_B + ESUM_B;           // 180.8e6
    if (ws_size < NEED) return;  // graceful fail (diagnostic) instead of OOB crash

    char* ws = (char*)d_ws;
    __half* hs   = (__half*)(ws);
    __half* ssrc = (__half*)(ws + HS_B);
    __half* sdst = (__half*)(ws + 2 * HS_B);
    float*  agg  = (float*)(ws + HS_B);          // aliases ssrc+sdst (dead after K2)
    float*  eatt = (float*)(ws + 3 * HS_B);
    float*  esum = (float*)(ws + 3 * HS_B + EATT_B);

    k_node_embed<<<NN / NPB, 256, 0, stream>>>(x, Wi1, bi1, Wi2, bi2, Wa1, hs, ssrc, sdst);
    hipMemsetAsync(esum, 0, ESUM_B, stream);
    k_edge_att<<<NE / 4, 256, 0, stream>>>(ei, ssrc, sdst, ba1, Wa2, ba2, eatt, esum);
    hipMemsetAsync(agg, 0, (size_t)NN * HF * sizeof(float), stream);
    k_aggregate<<<NE / 4, 256, 0, stream>>>(ei, hs, eatt, esum, agg);
    k_out_mlp<<<NN / NPB, 256, 0, stream>>>(agg, Wf1, bf1, Wf2, bf2, out);
}

// Round 3
// 1508.374 us; speedup vs baseline: 4.0982x; 4.0982x over previous
//
#include <hip/hip_runtime.h>
#include <hip/hip_bf16.h>
#include <hip/hip_fp16.h>

#define NN 100000
#define NE 1600000
#define HEADS 4
#define EM 64
#define HF 256      // HEADS*EM
#define IN_DIM 128
#define HI 64
#define OUT_DIM 128

__device__ __forceinline__ float lrelu(float x) { return x > 0.f ? x : 0.01f * x; }

struct H4 { __half2 a, b; };   // 4 fp16 = 8 bytes

// ---------------- Kernel 1: per-head node MLP + attention projections ----------------
#define NPB 8
__global__ __launch_bounds__(256) void k_node_embed(
    const float* __restrict__ x,
    const float* __restrict__ Wi1, const float* __restrict__ bi1,
    const float* __restrict__ Wi2, const float* __restrict__ bi2,
    const float* __restrict__ Wa1,
    __half* __restrict__ hs, __half* __restrict__ ssrc, __half* __restrict__ sdst)
{
    __shared__ float xs[NPB][IN_DIM];
    __shared__ float h1s[NPB][HF];
    __shared__ float hss[NPB][HF];
    const int t = threadIdx.x;
    const int nbase = blockIdx.x * NPB;

    {
        int i = t >> 5;
        int f = (t & 31) << 2;
        float4 v = *(const float4*)(x + (size_t)(nbase + i) * IN_DIM + f);
        xs[i][f] = v.x; xs[i][f + 1] = v.y; xs[i][f + 2] = v.z; xs[i][f + 3] = v.w;
    }
    __syncthreads();

    const int h = t >> 6, k = t & 63;
    float acc[NPB];

    // layer 1: 128 -> 64 per head
    {
        const float* w = Wi1 + (size_t)h * IN_DIM * EM + k;
        #pragma unroll
        for (int i = 0; i < NPB; ++i) acc[i] = 0.f;
        for (int f = 0; f < IN_DIM; ++f) {
            float wv = w[f * EM];
            #pragma unroll
            for (int i = 0; i < NPB; ++i) acc[i] = fmaf(xs[i][f], wv, acc[i]);
        }
        float b = bi1[h * EM + k];
        #pragma unroll
        for (int i = 0; i < NPB; ++i) h1s[i][t] = lrelu(acc[i] + b);
    }
    __syncthreads();

    // layer 2: 64 -> 64 per head
    {
        const float* w = Wi2 + (size_t)h * EM * EM + k;
        #pragma unroll
        for (int i = 0; i < NPB; ++i) acc[i] = 0.f;
        for (int f = 0; f < EM; ++f) {
            float wv = w[f * EM];
            #pragma unroll
            for (int i = 0; i < NPB; ++i) acc[i] = fmaf(h1s[i][h * EM + f], wv, acc[i]);
        }
        float b = bi2[h * EM + k];
        #pragma unroll
        for (int i = 0; i < NPB; ++i) {
            float v = acc[i] + b;
            hss[i][t] = v;
            hs[(size_t)(nbase + i) * HF + t] = __float2half_rn(v);
        }
    }
    __syncthreads();

    // attention projections
    {
        const float* w = Wa1 + (size_t)h * (2 * EM) * HI + k;
        float accs[NPB], accd[NPB];
        #pragma unroll
        for (int i = 0; i < NPB; ++i) { accs[i] = 0.f; accd[i] = 0.f; }
        for (int f = 0; f < EM; ++f) {
            float wsv = w[f * HI];
            float wdv = w[(EM + f) * HI];
            #pragma unroll
            for (int i = 0; i < NPB; ++i) {
                float hv = hss[i][h * EM + f];
                accs[i] = fmaf(hv, wsv, accs[i]);
                accd[i] = fmaf(hv, wdv, accd[i]);
            }
        }
        #pragma unroll
        for (int i = 0; i < NPB; ++i) {
            ssrc[(size_t)(nbase + i) * HF + t] = __float2half_rn(accs[i]);
            sdst[(size_t)(nbase + i) * HF + t] = __float2half_rn(accd[i]);
        }
    }
}

// ---------------- CSR build: degree count ----------------
__global__ __launch_bounds__(256) void k_deg(const int* __restrict__ ei, int* __restrict__ deg)
{
    int e = blockIdx.x * 256 + threadIdx.x;
    if (e < NE) atomicAdd(deg + ei[NE + e], 1);
}

// ---------------- CSR build: single-block exclusive scan ----------------
__global__ __launch_bounds__(256) void k_scan(const int* __restrict__ deg,
                                              int* __restrict__ rowptr, int* __restrict__ cur)
{
    __shared__ int wsum[4], woff[4];
    __shared__ int base, ctot;
    const int t = threadIdx.x, lane = t & 63, w = t >> 6;
    if (t == 0) base = 0;
    __syncthreads();

    for (int start = 0; start < NN; start += 256) {
        int i = start + t;
        int v = (i < NN) ? deg[i] : 0;
        int incl = v;
        #pragma unroll
        for (int d = 1; d < 64; d <<= 1) {
            int u = __shfl_up(incl, d);
            if (lane >= d) incl += u;
        }
        if (lane == 63) wsum[w] = incl;
        __syncthreads();
        if (t == 0) {
            int s = 0;
            #pragma unroll
            for (int j = 0; j < 4; ++j) { int xv = wsum[j]; woff[j] = s; s += xv; }
            ctot = s;
        }
        __syncthreads();
        if (i < NN) {
            int excl = base + woff[w] + incl - v;
            rowptr[i] = excl;
            cur[i] = excl;
        }
        __syncthreads();
        if (t == 0) base += ctot;
        __syncthreads();
    }
    if (threadIdx.x == 0) rowptr[NN] = base;
}

// ---------------- CSR build: fill edge list ----------------
__global__ __launch_bounds__(256) void k_fill(const int* __restrict__ ei,
                                              int* __restrict__ cur, int* __restrict__ elist)
{
    int e = blockIdx.x * 256 + threadIdx.x;
    if (e < NE) {
        int pos = atomicAdd(cur + ei[NE + e], 1);
        elist[pos] = e;
    }
}

// ---------------- Kernel 2: per-edge attention logits + exp + softmax denom ----------------
__global__ __launch_bounds__(256) void k_edge_att(
    const int* __restrict__ ei,
    const __half* __restrict__ ssrc, const __half* __restrict__ sdst,
    const float* __restrict__ ba1, const float* __restrict__ Wa2, const float* __restrict__ ba2,
    __half* __restrict__ eatt, float* __restrict__ esum)
{
    const int wave = threadIdx.x >> 6;
    const int lane = threadIdx.x & 63;
    const int e = blockIdx.x * 4 + wave;
    if (e >= NE) return;
    const int src = ei[e];
    const int dst = ei[NE + e];
    const int h = lane >> 4;
    const int kq = lane & 15;
    const int kb = h * EM + kq * 4;

    H4 vs = ((const H4*)(ssrc + (size_t)src * HF))[lane];
    H4 vd = ((const H4*)(sdst + (size_t)dst * HF))[lane];
    float2 s0 = __half22float2(vs.a), s1 = __half22float2(vs.b);
    float2 d0 = __half22float2(vd.a), d1 = __half22float2(vd.b);

    float t0 = lrelu(s0.x + d0.x + ba1[kb + 0]);
    float t1 = lrelu(s0.y + d0.y + ba1[kb + 1]);
    float t2 = lrelu(s1.x + d1.x + ba1[kb + 2]);
    float t3 = lrelu(s1.y + d1.y + ba1[kb + 3]);

    const float* w2 = Wa2 + h * EM + kq * 4;
    float p = t0 * w2[0] + t1 * w2[1] + t2 * w2[2] + t3 * w2[3];
    p += __shfl_xor(p, 1);
    p += __shfl_xor(p, 2);
    p += __shfl_xor(p, 4);
    p += __shfl_xor(p, 8);

    if (kq == 0) {
        float a = lrelu(p + ba2[h]);
        float eh = expf(a);
        eatt[(size_t)e * HEADS + h] = __float2half_rn(eh);
        unsafeAtomicAdd(esum + (size_t)src * HEADS + h, eh);
    }
}

// ---------------- Kernel 3: CSR gather aggregation (no f32 atomics) ----------------
// one wave per dst node; 64 lanes x 4 floats = 256-wide accumulator in registers
__global__ __launch_bounds__(256) void k_aggregate_csr(
    const int* __restrict__ ei,
    const int* __restrict__ rowptr, const int* __restrict__ elist,
    const __half* __restrict__ hs,
    const __half* __restrict__ eatt, const float* __restrict__ esum,
    float* __restrict__ agg)
{
    const int wave = threadIdx.x >> 6;
    const int lane = threadIdx.x & 63;
    const int n = blockIdx.x * 4 + wave;     // NN divisible by 4
    const int h = lane >> 4;

    const int beg = rowptr[n], end = rowptr[n + 1];
    float a0 = 0.f, a1 = 0.f, a2 = 0.f, a3 = 0.f;

    int p = beg;
    int e_cur = 0, src_cur = 0;
    if (p < end) { e_cur = elist[p]; src_cur = ei[e_cur]; }
    while (p < end) {
        const int e = e_cur, src = src_cur;
        const int pn = p + 1;
        if (pn < end) { e_cur = elist[pn]; src_cur = ei[e_cur]; }  // prefetch next

        float al = __half2float(eatt[(size_t)e * HEADS + h]) /
                   esum[(size_t)src * HEADS + h];
        H4 hv = ((const H4*)(hs + (size_t)src * HF))[lane];
        float2 h0 = __half22float2(hv.a), h1 = __half22float2(hv.b);
        a0 = fmaf(h0.x, al, a0);
        a1 = fmaf(h0.y, al, a1);
        a2 = fmaf(h1.x, al, a2);
        a3 = fmaf(h1.y, al, a3);
        p = pn;
    }
    *(float4*)(agg + (size_t)n * HF + lane * 4) = make_float4(a0, a1, a2, a3);
}

// ---------------- Kernel 4: output MLP 256 -> 64 (leaky) -> 128 ----------------
__global__ __launch_bounds__(256) void k_out_mlp(
    const float* __restrict__ agg,
    const float* __restrict__ Wf1, const float* __restrict__ bf1,
    const float* __restrict__ Wf2, const float* __restrict__ bf2,
    float* __restrict__ out)
{
    __shared__ float aggL[NPB][HF];
    __shared__ float midL[NPB][HI];
    const int t = threadIdx.x;
    const int nbase = blockIdx.x * NPB;

    {
        int i = t >> 5;
        int f = (t & 31) << 3;
        const float4* p = (const float4*)(agg + (size_t)(nbase + i) * HF + f);
        float4 a = p[0], b = p[1];
        aggL[i][f + 0] = a.x; aggL[i][f + 1] = a.y; aggL[i][f + 2] = a.z; aggL[i][f + 3] = a.w;
        aggL[i][f + 4] = b.x; aggL[i][f + 5] = b.y; aggL[i][f + 6] = b.z; aggL[i][f + 7] = b.w;
    }
    __syncthreads();

    {
        int k = t & 63, g = t >> 6;
        float a0 = 0.f, a1 = 0.f;
        for (int f = 0; f < HF; ++f) {
            float w = Wf1[f * HI + k];
            a0 = fmaf(aggL[g][f], w, a0);
            a1 = fmaf(aggL[g + 4][f], w, a1);
        }
        float b = bf1[k];
        midL[g][k] = lrelu(a0 + b);
        midL[g + 4][k] = lrelu(a1 + b);
    }
    __syncthreads();

    {
        int o = t & 127, g2 = t >> 7;
        float c0 = 0.f, c1 = 0.f, c2 = 0.f, c3 = 0.f;
        for (int f = 0; f < HI; ++f) {
            float w = Wf2[f * OUT_DIM + o];
            c0 = fmaf(midL[g2 + 0][f], w, c0);
            c1 = fmaf(midL[g2 + 2][f], w, c1);
            c2 = fmaf(midL[g2 + 4][f], w, c2);
            c3 = fmaf(midL[g2 + 6][f], w, c3);
        }
        float b = bf2[o];
        out[(size_t)(nbase + g2 + 0) * OUT_DIM + o] = c0 + b;
        out[(size_t)(nbase + g2 + 2) * OUT_DIM + o] = c1 + b;
        out[(size_t)(nbase + g2 + 4) * OUT_DIM + o] = c2 + b;
        out[(size_t)(nbase + g2 + 6) * OUT_DIM + o] = c3 + b;
    }
}

extern "C" void kernel_launch(void* const* d_in, const int* in_sizes, int n_in,
                              void* d_out, int out_size, void* d_ws, size_t ws_size,
                              hipStream_t stream) {
    const float* x   = (const float*)d_in[0];
    const int*   ei  = (const int*)d_in[1];
    const float* Wi1 = (const float*)d_in[2];
    const float* bi1 = (const float*)d_in[3];
    const float* Wi2 = (const float*)d_in[4];
    const float* bi2 = (const float*)d_in[5];
    const float* Wa1 = (const float*)d_in[6];
    const float* ba1 = (const float*)d_in[7];
    const float* Wa2 = (const float*)d_in[8];
    const float* ba2 = (const float*)d_in[9];
    const float* Wf1 = (const float*)d_in[10];
    const float* bf1 = (const float*)d_in[11];
    const float* Wf2 = (const float*)d_in[12];
    const float* bf2 = (const float*)d_in[13];
    float* out = (float*)d_out;

    // workspace layout:
    //   hs   (half NN*HF)                      [0,               51.2e6)
    //   ssrc (half NN*HF)  } aliased by agg    [51.2e6,         102.4e6)
    //   sdst (half NN*HF)  } (f32 NN*HF)       [102.4e6,        153.6e6)
    //   eatt (half NE*H)                       [153.6e6,        166.4e6)
    //   esum (f32  NN*H)                       [166.4e6,        168.0e6)
    //   rowptr (int NN+1)                      [168.0e6,       ~168.4e6)
    //   cur/deg (int NN)                       [168.5e6,       ~168.9e6)
    //   elist (int NE)                         [169.0e6,        175.4e6)
    const size_t HS_B   = (size_t)NN * HF * sizeof(__half);
    const size_t EATT_B = (size_t)NE * HEADS * sizeof(__half);
    const size_t ESUM_B = (size_t)NN * HEADS * sizeof(float);
    const size_t RP_B   = (size_t)(NN + 1) * sizeof(int);
    const size_t CUR_B  = (size_t)NN * sizeof(int);
    const size_t EL_B   = (size_t)NE * sizeof(int);
    const size_t OFF_EATT = 3 * HS_B;
    const size_t OFF_ESUM = OFF_EATT + EATT_B;
    const size_t OFF_RP   = OFF_ESUM + ESUM_B;
    const size_t OFF_CUR  = OFF_RP + RP_B;
    const size_t OFF_EL   = OFF_CUR + CUR_B;
    const size_t NEED     = OFF_EL + EL_B;       // ~175.6 MB (< 180.8 proven OK)
    if (ws_size < NEED) return;

    char* ws = (char*)d_ws;
    __half* hs   = (__half*)(ws);
    __half* ssrc = (__half*)(ws + HS_B);
    __half* sdst = (__half*)(ws + 2 * HS_B);
    float*  agg  = (float*)(ws + HS_B);          // aliases ssrc+sdst (dead after K2)
    __half* eatt = (__half*)(ws + OFF_EATT);
    float*  esum = (float*)(ws + OFF_ESUM);
    int* rowptr  = (int*)(ws + OFF_RP);
    int* cur     = (int*)(ws + OFF_CUR);
    int* elist   = (int*)(ws + OFF_EL);
    int* deg     = cur;                          // deg counted, then scan converts to cursor

    k_node_embed<<<NN / NPB, 256, 0, stream>>>(x, Wi1, bi1, Wi2, bi2, Wa1, hs, ssrc, sdst);
    hipMemsetAsync(esum, 0, ESUM_B, stream);
    hipMemsetAsync(deg, 0, CUR_B, stream);
    k_deg<<<NE / 256, 256, 0, stream>>>(ei, deg);
    k_scan<<<1, 256, 0, stream>>>(deg, rowptr, cur);
    k_fill<<<NE / 256, 256, 0, stream>>>(ei, cur, elist);
    k_edge_att<<<NE / 4, 256, 0, stream>>>(ei, ssrc, sdst, ba1, Wa2, ba2, eatt, esum);
    k_aggregate_csr<<<NN / 4, 256, 0, stream>>>(ei, rowptr, elist, hs, eatt, esum, agg);
    k_out_mlp<<<NN / NPB, 256, 0, stream>>>(agg, Wf1, bf1, Wf2, bf2, out);
}

// Round 4
// 1328.418 us; speedup vs baseline: 4.6534x; 1.1355x over previous
//
#include <hip/hip_runtime.h>
#include <hip/hip_bf16.h>
#include <hip/hip_fp16.h>

#define NN 100000
#define NE 1600000
#define HEADS 4
#define EM 64
#define HF 256      // HEADS*EM
#define IN_DIM 128
#define HI 64
#define OUT_DIM 128
#define NB_SCAN 391  // ceil(NN/256)

__device__ __forceinline__ float lrelu(float x) { return x > 0.f ? x : 0.01f * x; }

struct H4 { __half2 a, b; };        // 4 fp16 = 8 bytes
struct H8 { __half2 a, b, c, d; };  // 8 fp16 = 16 bytes

// ---------------- Kernel 1: per-head node MLP + attention projections ----------------
#define NPB 8
__global__ __launch_bounds__(256) void k_node_embed(
    const float* __restrict__ x,
    const float* __restrict__ Wi1, const float* __restrict__ bi1,
    const float* __restrict__ Wi2, const float* __restrict__ bi2,
    const float* __restrict__ Wa1,
    __half* __restrict__ hs, __half* __restrict__ ssrc, __half* __restrict__ sdst)
{
    __shared__ float xs[NPB][IN_DIM];
    __shared__ float h1s[NPB][HF];
    __shared__ float hss[NPB][HF];
    const int t = threadIdx.x;
    const int nbase = blockIdx.x * NPB;

    {
        int i = t >> 5;
        int f = (t & 31) << 2;
        float4 v = *(const float4*)(x + (size_t)(nbase + i) * IN_DIM + f);
        xs[i][f] = v.x; xs[i][f + 1] = v.y; xs[i][f + 2] = v.z; xs[i][f + 3] = v.w;
    }
    __syncthreads();

    const int h = t >> 6, k = t & 63;
    float acc[NPB];

    // layer 1: 128 -> 64 per head (float4 LDS reads, 4x fewer ds ops)
    {
        const float* w = Wi1 + (size_t)h * IN_DIM * EM + k;
        #pragma unroll
        for (int i = 0; i < NPB; ++i) acc[i] = 0.f;
        for (int f = 0; f < IN_DIM; f += 4) {
            float w0 = w[f * EM], w1 = w[(f + 1) * EM], w2 = w[(f + 2) * EM], w3 = w[(f + 3) * EM];
            #pragma unroll
            for (int i = 0; i < NPB; ++i) {
                float4 xv = *(const float4*)&xs[i][f];
                acc[i] = fmaf(xv.x, w0, fmaf(xv.y, w1, fmaf(xv.z, w2, fmaf(xv.w, w3, acc[i]))));
            }
        }
        float b = bi1[h * EM + k];
        #pragma unroll
        for (int i = 0; i < NPB; ++i) h1s[i][t] = lrelu(acc[i] + b);
    }
    __syncthreads();

    // layer 2: 64 -> 64 per head
    {
        const float* w = Wi2 + (size_t)h * EM * EM + k;
        #pragma unroll
        for (int i = 0; i < NPB; ++i) acc[i] = 0.f;
        for (int f = 0; f < EM; f += 4) {
            float w0 = w[f * EM], w1 = w[(f + 1) * EM], w2 = w[(f + 2) * EM], w3 = w[(f + 3) * EM];
            #pragma unroll
            for (int i = 0; i < NPB; ++i) {
                float4 xv = *(const float4*)&h1s[i][h * EM + f];
                acc[i] = fmaf(xv.x, w0, fmaf(xv.y, w1, fmaf(xv.z, w2, fmaf(xv.w, w3, acc[i]))));
            }
        }
        float b = bi2[h * EM + k];
        #pragma unroll
        for (int i = 0; i < NPB; ++i) {
            float v = acc[i] + b;
            hss[i][t] = v;
            hs[(size_t)(nbase + i) * HF + t] = __float2half_rn(v);
        }
    }
    __syncthreads();

    // attention projections: ssrc / sdst
    {
        const float* w = Wa1 + (size_t)h * (2 * EM) * HI + k;
        float accs[NPB], accd[NPB];
        #pragma unroll
        for (int i = 0; i < NPB; ++i) { accs[i] = 0.f; accd[i] = 0.f; }
        for (int f = 0; f < EM; f += 4) {
            float ws0 = w[f * HI], ws1 = w[(f + 1) * HI], ws2 = w[(f + 2) * HI], ws3 = w[(f + 3) * HI];
            float wd0 = w[(EM + f) * HI], wd1 = w[(EM + f + 1) * HI], wd2 = w[(EM + f + 2) * HI], wd3 = w[(EM + f + 3) * HI];
            #pragma unroll
            for (int i = 0; i < NPB; ++i) {
                float4 hv = *(const float4*)&hss[i][h * EM + f];
                accs[i] = fmaf(hv.x, ws0, fmaf(hv.y, ws1, fmaf(hv.z, ws2, fmaf(hv.w, ws3, accs[i]))));
                accd[i] = fmaf(hv.x, wd0, fmaf(hv.y, wd1, fmaf(hv.z, wd2, fmaf(hv.w, wd3, accd[i]))));
            }
        }
        #pragma unroll
        for (int i = 0; i < NPB; ++i) {
            ssrc[(size_t)(nbase + i) * HF + t] = __float2half_rn(accs[i]);
            sdst[(size_t)(nbase + i) * HF + t] = __float2half_rn(accd[i]);
        }
    }
}

// ---------------- CSR build ----------------
__global__ __launch_bounds__(256) void k_deg(const int* __restrict__ idx, int* __restrict__ cnt)
{
    int e = blockIdx.x * 256 + threadIdx.x;   // grid sized exactly NE/256
    atomicAdd(cnt + idx[e], 1);
}

// block sums
__global__ __launch_bounds__(256) void k_scan1(const int* __restrict__ arr, int* __restrict__ bsum)
{
    const int t = threadIdx.x, lane = t & 63, w = t >> 6;
    int i = blockIdx.x * 256 + t;
    int v = (i < NN) ? arr[i] : 0;
    #pragma unroll
    for (int d = 1; d < 64; d <<= 1) v += __shfl_xor(v, d);
    __shared__ int ws[4];
    if (lane == 0) ws[w] = v;
    __syncthreads();
    if (t == 0) bsum[blockIdx.x] = ws[0] + ws[1] + ws[2] + ws[3];
}

// exclusive scan of NB_SCAN block sums (single block)
__global__ __launch_bounds__(256) void k_scan2(int* __restrict__ bsum)
{
    __shared__ int wsum[4], woff[4];
    __shared__ int base, ctot;
    const int t = threadIdx.x, lane = t & 63, w = t >> 6;
    if (t == 0) base = 0;
    __syncthreads();
    for (int start = 0; start < NB_SCAN; start += 256) {
        int i = start + t;
        int v = (i < NB_SCAN) ? bsum[i] : 0;
        int incl = v;
        #pragma unroll
        for (int d = 1; d < 64; d <<= 1) {
            int u = __shfl_up(incl, d);
            if (lane >= d) incl += u;
        }
        if (lane == 63) wsum[w] = incl;
        __syncthreads();
        if (t == 0) {
            int s = 0;
            #pragma unroll
            for (int j = 0; j < 4; ++j) { int xv = wsum[j]; woff[j] = s; s += xv; }
            ctot = s;
        }
        __syncthreads();
        if (i < NB_SCAN) bsum[i] = base + woff[w] + incl - v;  // exclusive
        __syncthreads();
        if (t == 0) base += ctot;
        __syncthreads();
    }
}

// per-block rescan: arr -> global exclusive prefix (in place)
__global__ __launch_bounds__(256) void k_scan3(int* __restrict__ arr, const int* __restrict__ bsum)
{
    const int t = threadIdx.x, lane = t & 63, w = t >> 6;
    int i = blockIdx.x * 256 + t;
    int v = (i < NN) ? arr[i] : 0;
    int incl = v;
    #pragma unroll
    for (int d = 1; d < 64; d <<= 1) {
        int u = __shfl_up(incl, d);
        if (lane >= d) incl += u;
    }
    __shared__ int wsum[4], woff[4];
    if (lane == 63) wsum[w] = incl;
    __syncthreads();
    if (t == 0) {
        int s = 0;
        #pragma unroll
        for (int j = 0; j < 4; ++j) { int xv = wsum[j]; woff[j] = s; s += xv; }
    }
    __syncthreads();
    if (i < NN) arr[i] = bsum[blockIdx.x] + woff[w] + incl - v;
}

__global__ __launch_bounds__(256) void k_fill(const int* __restrict__ idx,
                                              int* __restrict__ cur, int* __restrict__ lst)
{
    int e = blockIdx.x * 256 + threadIdx.x;
    int pos = atomicAdd(cur + idx[e], 1);
    lst[pos] = e;
}

// ---------------- Pass A: src-CSR attention (no atomics) + in-place hs normalize ----------------
// one wave per src node; after k_fill, cur_s[n] = end ptr, cur_s[n-1] = begin ptr
__global__ __launch_bounds__(256) void k_edge_att_csr(
    const int* __restrict__ ei, const int* __restrict__ es, const int* __restrict__ cur_s,
    const __half* __restrict__ ssrc, const __half* __restrict__ sdst,
    const float* __restrict__ ba1, const float* __restrict__ Wa2, const float* __restrict__ ba2,
    __half* __restrict__ eatt, __half* __restrict__ hs)
{
    const int wave = threadIdx.x >> 6;
    const int lane = threadIdx.x & 63;
    const int n = blockIdx.x * 4 + wave;     // NN divisible by 4
    const int h = lane >> 4;
    const int kq = lane & 15;

    const int beg = (n == 0) ? 0 : cur_s[n - 1];
    const int end = cur_s[n];
    if (beg >= end) return;

    const float4 ba1v = *(const float4*)(ba1 + h * EM + kq * 4);
    const float4 w2v  = *(const float4*)(Wa2 + h * EM + kq * 4);
    const float  ba2v = ba2[h];

    H4 sv = ((const H4*)(ssrc + (size_t)n * HF))[lane];
    float2 s0 = __half22float2(sv.a), s1 = __half22float2(sv.b);
    const float z0 = s0.x + ba1v.x, z1 = s0.y + ba1v.y;
    const float z2 = s1.x + ba1v.z, z3 = s1.y + ba1v.w;

    float esum = 0.f;
    int p = beg;
    int e_n = es[p];
    int d_n = ei[NE + e_n];
    while (p < end) {
        const int e = e_n, dst = d_n;
        if (p + 1 < end) { e_n = es[p + 1]; d_n = ei[NE + e_n]; }

        H4 dv = ((const H4*)(sdst + (size_t)dst * HF))[lane];
        float2 d0 = __half22float2(dv.a), d1 = __half22float2(dv.b);
        float t0 = lrelu(z0 + d0.x), t1 = lrelu(z1 + d0.y);
        float t2 = lrelu(z2 + d1.x), t3 = lrelu(z3 + d1.y);
        float pv = fmaf(t0, w2v.x, fmaf(t1, w2v.y, fmaf(t2, w2v.z, t3 * w2v.w)));
        pv += __shfl_xor(pv, 1);
        pv += __shfl_xor(pv, 2);
        pv += __shfl_xor(pv, 4);
        pv += __shfl_xor(pv, 8);
        float a = lrelu(pv + ba2v);
        float eh = __expf(a);
        esum += eh;
        if (kq == 0) eatt[(size_t)e * HEADS + h] = __float2half_rn(eh);
        ++p;
    }

    // fold 1/esum into hs (in place; hs row is owned by this wave only)
    float inv = 1.f / esum;
    H4* hrow = (H4*)(hs + (size_t)n * HF);
    H4 hv = hrow[lane];
    float2 h0 = __half22float2(hv.a), h1 = __half22float2(hv.b);
    H4 o;
    o.a = __floats2half2_rn(h0.x * inv, h0.y * inv);
    o.b = __floats2half2_rn(h1.x * inv, h1.y * inv);
    hrow[lane] = o;
}

// ---------------- Pass B: dst-CSR gather aggregation ----------------
__global__ __launch_bounds__(256) void k_aggregate_csr(
    const int* __restrict__ ei, const int* __restrict__ ed, const int* __restrict__ cur_d,
    const __half* __restrict__ hs, const __half* __restrict__ eatt,
    __half* __restrict__ agg)
{
    const int wave = threadIdx.x >> 6;
    const int lane = threadIdx.x & 63;
    const int n = blockIdx.x * 4 + wave;
    const int h = lane >> 4;

    const int beg = (n == 0) ? 0 : cur_d[n - 1];
    const int end = cur_d[n];
    float a0 = 0.f, a1 = 0.f, a2 = 0.f, a3 = 0.f;

    int p = beg;
    int e_n = 0, s_n = 0;
    if (p < end) { e_n = ed[p]; s_n = ei[e_n]; }
    while (p < end) {
        const int e = e_n, src = s_n;
        if (p + 1 < end) { e_n = ed[p + 1]; s_n = ei[e_n]; }

        float al = __half2float(eatt[(size_t)e * HEADS + h]);
        H4 hv = ((const H4*)(hs + (size_t)src * HF))[lane];
        float2 h0 = __half22float2(hv.a), h1 = __half22float2(hv.b);
        a0 = fmaf(h0.x, al, a0);
        a1 = fmaf(h0.y, al, a1);
        a2 = fmaf(h1.x, al, a2);
        a3 = fmaf(h1.y, al, a3);
        ++p;
    }
    H4 o;
    o.a = __floats2half2_rn(a0, a1);
    o.b = __floats2half2_rn(a2, a3);
    ((H4*)(agg + (size_t)n * HF))[lane] = o;
}

// ---------------- Kernel 4: output MLP 256 -> 64 (leaky) -> 128 ----------------
__global__ __launch_bounds__(256) void k_out_mlp(
    const __half* __restrict__ agg,
    const float* __restrict__ Wf1, const float* __restrict__ bf1,
    const float* __restrict__ Wf2, const float* __restrict__ bf2,
    float* __restrict__ out)
{
    __shared__ float aggL[NPB][HF];
    __shared__ float midL[NPB][HI];
    const int t = threadIdx.x;
    const int nbase = blockIdx.x * NPB;

    {
        int i = t >> 5;
        int f = (t & 31) << 3;
        H8 v = *(const H8*)(agg + (size_t)(nbase + i) * HF + f);
        float2 f0 = __half22float2(v.a), f1 = __half22float2(v.b);
        float2 f2 = __half22float2(v.c), f3 = __half22float2(v.d);
        aggL[i][f + 0] = f0.x; aggL[i][f + 1] = f0.y; aggL[i][f + 2] = f1.x; aggL[i][f + 3] = f1.y;
        aggL[i][f + 4] = f2.x; aggL[i][f + 5] = f2.y; aggL[i][f + 6] = f3.x; aggL[i][f + 7] = f3.y;
    }
    __syncthreads();

    {
        int k = t & 63, g = t >> 6;
        float a0 = 0.f, a1 = 0.f;
        for (int f = 0; f < HF; ++f) {
            float w = Wf1[f * HI + k];
            a0 = fmaf(aggL[g][f], w, a0);
            a1 = fmaf(aggL[g + 4][f], w, a1);
        }
        float b = bf1[k];
        midL[g][k] = lrelu(a0 + b);
        midL[g + 4][k] = lrelu(a1 + b);
    }
    __syncthreads();

    {
        int o = t & 127, g2 = t >> 7;
        float c0 = 0.f, c1 = 0.f, c2 = 0.f, c3 = 0.f;
        for (int f = 0; f < HI; ++f) {
            float w = Wf2[f * OUT_DIM + o];
            c0 = fmaf(midL[g2 + 0][f], w, c0);
            c1 = fmaf(midL[g2 + 2][f], w, c1);
            c2 = fmaf(midL[g2 + 4][f], w, c2);
            c3 = fmaf(midL[g2 + 6][f], w, c3);
        }
        float b = bf2[o];
        out[(size_t)(nbase + g2 + 0) * OUT_DIM + o] = c0 + b;
        out[(size_t)(nbase + g2 + 2) * OUT_DIM + o] = c1 + b;
        out[(size_t)(nbase + g2 + 4) * OUT_DIM + o] = c2 + b;
        out[(size_t)(nbase + g2 + 6) * OUT_DIM + o] = c3 + b;
    }
}

extern "C" void kernel_launch(void* const* d_in, const int* in_sizes, int n_in,
                              void* d_out, int out_size, void* d_ws, size_t ws_size,
                              hipStream_t stream) {
    const float* x   = (const float*)d_in[0];
    const int*   ei  = (const int*)d_in[1];
    const float* Wi1 = (const float*)d_in[2];
    const float* bi1 = (const float*)d_in[3];
    const float* Wi2 = (const float*)d_in[4];
    const float* bi2 = (const float*)d_in[5];
    const float* Wa1 = (const float*)d_in[6];
    const float* ba1 = (const float*)d_in[7];
    const float* Wa2 = (const float*)d_in[8];
    const float* ba2 = (const float*)d_in[9];
    const float* Wf1 = (const float*)d_in[10];
    const float* bf1 = (const float*)d_in[11];
    const float* Wf2 = (const float*)d_in[12];
    const float* bf2 = (const float*)d_in[13];
    float* out = (float*)d_out;

    // static layout (bytes):
    //   hs    [0,        51.2e6)   half NN*HF   (normalized in place by pass A)
    //   ssrc  [51.2e6,  102.4e6)   half         -> agg (half) aliases after pass A
    //   sdst  [102.4e6, 153.6e6)   half         -> ed (int NE, 6.4e6) aliases after pass A
    //   eatt  [153.6e6, 166.4e6)   half NE*H
    //   cur_s [166.4e6, 166.8e6)   int NN
    //   cur_d [166.8e6, 167.2e6)   int NN
    //   bsum  [167.2e6, +4096)     int NB_SCAN
    //   es    [167.204e6, 173.604e6) int NE
    const size_t HS_B = (size_t)NN * HF * sizeof(__half);      // 51.2e6
    const size_t OFF_SSRC = HS_B;
    const size_t OFF_SDST = 2 * HS_B;
    const size_t OFF_EATT = 3 * HS_B;
    const size_t OFF_CURS = OFF_EATT + (size_t)NE * HEADS * sizeof(__half);
    const size_t OFF_CURD = OFF_CURS + (size_t)NN * sizeof(int);
    const size_t OFF_BSUM = OFF_CURD + (size_t)NN * sizeof(int);
    const size_t OFF_ES   = OFF_BSUM + 4096;
    const size_t NEED     = OFF_ES + (size_t)NE * sizeof(int); // ~173.6 MB (< 175.6 proven)
    if (ws_size < NEED) return;

    char* ws = (char*)d_ws;
    __half* hs   = (__half*)(ws);
    __half* ssrc = (__half*)(ws + OFF_SSRC);
    __half* sdst = (__half*)(ws + OFF_SDST);
    __half* eatt = (__half*)(ws + OFF_EATT);
    int* cur_s   = (int*)(ws + OFF_CURS);
    int* cur_d   = (int*)(ws + OFF_CURD);
    int* bsum    = (int*)(ws + OFF_BSUM);
    int* es      = (int*)(ws + OFF_ES);
    __half* agg  = (__half*)(ws + OFF_SSRC);   // aliases ssrc (dead after pass A)
    int* ed      = (int*)(ws + OFF_SDST);      // aliases sdst (dead after pass A)

    k_node_embed<<<NN / NPB, 256, 0, stream>>>(x, Wi1, bi1, Wi2, bi2, Wa1, hs, ssrc, sdst);

    // src-CSR
    hipMemsetAsync(cur_s, 0, (size_t)NN * sizeof(int), stream);
    k_deg<<<NE / 256, 256, 0, stream>>>(ei, cur_s);
    k_scan1<<<NB_SCAN, 256, 0, stream>>>(cur_s, bsum);
    k_scan2<<<1, 256, 0, stream>>>(bsum);
    k_scan3<<<NB_SCAN, 256, 0, stream>>>(cur_s, bsum);
    k_fill<<<NE / 256, 256, 0, stream>>>(ei, cur_s, es);

    // pass A
    k_edge_att_csr<<<NN / 4, 256, 0, stream>>>(ei, es, cur_s, ssrc, sdst, ba1, Wa2, ba2, eatt, hs);

    // dst-CSR (into dead sdst region)
    hipMemsetAsync(cur_d, 0, (size_t)NN * sizeof(int), stream);
    k_deg<<<NE / 256, 256, 0, stream>>>(ei + NE, cur_d);
    k_scan1<<<NB_SCAN, 256, 0, stream>>>(cur_d, bsum);
    k_scan2<<<1, 256, 0, stream>>>(bsum);
    k_scan3<<<NB_SCAN, 256, 0, stream>>>(cur_d, bsum);
    k_fill<<<NE / 256, 256, 0, stream>>>(ei + NE, cur_d, ed);

    // pass B
    k_aggregate_csr<<<NN / 4, 256, 0, stream>>>(ei, ed, cur_d, hs, eatt, agg);

    k_out_mlp<<<NN / NPB, 256, 0, stream>>>(agg, Wf1, bf1, Wf2, bf2, out);
}

// Round 5
// 1003.556 us; speedup vs baseline: 6.1597x; 1.3237x over previous
//
#include <hip/hip_runtime.h>
#include <hip/hip_bf16.h>
#include <hip/hip_fp16.h>

#define NN 100000
#define NE 1600000
#define HEADS 4
#define EM 64
#define HF 256      // HEADS*EM
#define IN_DIM 128
#define HI 64
#define OUT_DIM 128
#define NB_SCAN 391  // ceil(NN/256)

using f16 = _Float16;
typedef _Float16 f16x4 __attribute__((ext_vector_type(4)));
typedef float f32x4 __attribute__((ext_vector_type(4)));

__device__ __forceinline__ float lrelu(float x) { return x > 0.f ? x : 0.01f * x; }

struct H4 { __half2 a, b; };        // 4 fp16 = 8 bytes

// =====================================================================
// k_embed: fused node MLP + attention projections, MFMA 16x16x16 f16.
// Block = 64 nodes, 4 waves; wave h owns head h (64 output cols).
// Fragment layouts (16x16x16_f16):
//   A: lane l -> row = l&15,          k  = 4*(l>>4)+j
//   B: lane l -> k   = 4*(l>>4)+j,    col= l&15
//   C: lane l -> row = 4*(l>>4)+r,    col= l&15
// =====================================================================
__global__ __launch_bounds__(256) void k_embed(
    const float* __restrict__ x,
    const float* __restrict__ Wi1, const float* __restrict__ bi1,
    const float* __restrict__ Wi2, const float* __restrict__ bi2,
    const float* __restrict__ Wa1,
    f16* __restrict__ hs, f16* __restrict__ ssrc, f16* __restrict__ sdst)
{
    __shared__ __align__(16) char smem[73728];
    f16 (*xh)[136]      = (f16(*)[136])smem;            // 64x136 f16 = 17.4KB (region0)
    f16 (*hsL)[64][72]  = (f16(*)[64][72])smem;          // 4x64x72  = 36.9KB (region0 overlay)
    f16 (*h1L)[64][72]  = (f16(*)[64][72])(smem + 36864);// 4x64x72  = 36.9KB (region1)

    const int t = threadIdx.x;
    const int base = blockIdx.x * 64;

    // ---- stage x tile (64 x 128 f32 -> f16) ----
    #pragma unroll
    for (int i = 0; i < 8; ++i) {
        int q = t + i * 256;               // 0..2047 chunks of 4 floats
        int row = q >> 5;
        int c4 = (q & 31) << 2;
        int gr = base + row; if (gr >= NN) gr = NN - 1;
        float4 v = *(const float4*)(x + (size_t)gr * IN_DIM + c4);
        f16x4 hv = { (f16)v.x, (f16)v.y, (f16)v.z, (f16)v.w };
        *(f16x4*)&xh[row][c4] = hv;
    }
    __syncthreads();

    const int h = t >> 6;                  // wave = head
    const int l = t & 63;
    const int g = l >> 4;                  // lane group 0..3
    const int c = l & 15;                  // col-in-tile / row-in-A

    const f32x4 z4 = { 0.f, 0.f, 0.f, 0.f };

    // ---- GEMM1: h1 = lrelu(x * Wi1[h] + bi1[h]) ----
    f32x4 acc1[4][4];
    #pragma unroll
    for (int m = 0; m < 4; ++m)
        #pragma unroll
        for (int n = 0; n < 4; ++n) acc1[m][n] = z4;

    {
        const float* W = Wi1 + (size_t)h * IN_DIM * EM;
        for (int kc = 0; kc < 8; ++kc) {
            f16x4 bf[4];
            #pragma unroll
            for (int n = 0; n < 4; ++n) {
                const float* wp = W + (size_t)(kc * 16 + 4 * g) * EM + n * 16 + c;
                f16x4 b;
                b[0] = (f16)wp[0]; b[1] = (f16)wp[EM]; b[2] = (f16)wp[2 * EM]; b[3] = (f16)wp[3 * EM];
                bf[n] = b;
            }
            #pragma unroll
            for (int m = 0; m < 4; ++m) {
                f16x4 af = *(const f16x4*)&xh[m * 16 + c][kc * 16 + 4 * g];
                #pragma unroll
                for (int n = 0; n < 4; ++n)
                    acc1[m][n] = __builtin_amdgcn_mfma_f32_16x16x16f16(af, bf[n], acc1[m][n], 0, 0, 0);
            }
        }
    }
    __syncthreads();   // xh dead; region0 becomes hsL

    // epilogue GEMM1 -> h1L (private per wave)
    #pragma unroll
    for (int n = 0; n < 4; ++n) {
        float b = bi1[h * EM + n * 16 + c];
        #pragma unroll
        for (int m = 0; m < 4; ++m)
            #pragma unroll
            for (int r = 0; r < 4; ++r)
                h1L[h][m * 16 + 4 * g + r][n * 16 + c] = (f16)lrelu(acc1[m][n][r] + b);
    }
    __syncthreads();

    // ---- GEMM2: hs = h1 * Wi2[h] + bi2[h] ----
    f32x4 acc2[4][4];
    #pragma unroll
    for (int m = 0; m < 4; ++m)
        #pragma unroll
        for (int n = 0; n < 4; ++n) acc2[m][n] = z4;
    {
        const float* W = Wi2 + (size_t)h * EM * EM;
        for (int kc = 0; kc < 4; ++kc) {
            f16x4 bf[4];
            #pragma unroll
            for (int n = 0; n < 4; ++n) {
                const float* wp = W + (size_t)(kc * 16 + 4 * g) * EM + n * 16 + c;
                f16x4 b;
                b[0] = (f16)wp[0]; b[1] = (f16)wp[EM]; b[2] = (f16)wp[2 * EM]; b[3] = (f16)wp[3 * EM];
                bf[n] = b;
            }
            #pragma unroll
            for (int m = 0; m < 4; ++m) {
                f16x4 af = *(const f16x4*)&h1L[h][m * 16 + c][kc * 16 + 4 * g];
                #pragma unroll
                for (int n = 0; n < 4; ++n)
                    acc2[m][n] = __builtin_amdgcn_mfma_f32_16x16x16f16(af, bf[n], acc2[m][n], 0, 0, 0);
            }
        }
    }
    // epilogue GEMM2 -> hsL (private)
    #pragma unroll
    for (int n = 0; n < 4; ++n) {
        float b = bi2[h * EM + n * 16 + c];
        #pragma unroll
        for (int m = 0; m < 4; ++m)
            #pragma unroll
            for (int r = 0; r < 4; ++r)
                hsL[h][m * 16 + 4 * g + r][n * 16 + c] = (f16)(acc2[m][n][r] + b);
    }
    __syncthreads();

    // ---- GEMM3: ssrc = hs*Wa1[h][:64], sdst = hs*Wa1[h][64:] ----
    f16x4 af3[4][4];   // [m][kc]
    #pragma unroll
    for (int m = 0; m < 4; ++m)
        #pragma unroll
        for (int kc = 0; kc < 4; ++kc)
            af3[m][kc] = *(const f16x4*)&hsL[h][m * 16 + c][kc * 16 + 4 * g];

    const float* Wa = Wa1 + (size_t)h * (2 * EM) * HI;
    // 3a: ssrc -> h1L (region1, dead)
    {
        f32x4 acc3[4][4];
        #pragma unroll
        for (int m = 0; m < 4; ++m)
            #pragma unroll
            for (int n = 0; n < 4; ++n) acc3[m][n] = z4;
        for (int kc = 0; kc < 4; ++kc) {
            f16x4 bf[4];
            #pragma unroll
            for (int n = 0; n < 4; ++n) {
                const float* wp = Wa + (size_t)(kc * 16 + 4 * g) * HI + n * 16 + c;
                f16x4 b;
                b[0] = (f16)wp[0]; b[1] = (f16)wp[HI]; b[2] = (f16)wp[2 * HI]; b[3] = (f16)wp[3 * HI];
                bf[n] = b;
            }
            #pragma unroll
            for (int m = 0; m < 4; ++m)
                #pragma unroll
                for (int n = 0; n < 4; ++n)
                    acc3[m][n] = __builtin_amdgcn_mfma_f32_16x16x16f16(af3[m][kc], bf[n], acc3[m][n], 0, 0, 0);
        }
        #pragma unroll
        for (int n = 0; n < 4; ++n)
            #pragma unroll
            for (int m = 0; m < 4; ++m)
                #pragma unroll
                for (int r = 0; r < 4; ++r)
                    h1L[h][m * 16 + 4 * g + r][n * 16 + c] = (f16)acc3[m][n][r];
    }
    // 3b: sdst accs (kept in regs through the flush)
    f32x4 acc3b[4][4];
    #pragma unroll
    for (int m = 0; m < 4; ++m)
        #pragma unroll
        for (int n = 0; n < 4; ++n) acc3b[m][n] = z4;
    for (int kc = 0; kc < 4; ++kc) {
        f16x4 bf[4];
        #pragma unroll
        for (int n = 0; n < 4; ++n) {
            const float* wp = Wa + (size_t)(EM + kc * 16 + 4 * g) * HI + n * 16 + c;
            f16x4 b;
            b[0] = (f16)wp[0]; b[1] = (f16)wp[HI]; b[2] = (f16)wp[2 * HI]; b[3] = (f16)wp[3 * HI];
            bf[n] = b;
        }
        #pragma unroll
        for (int m = 0; m < 4; ++m)
            #pragma unroll
            for (int n = 0; n < 4; ++n)
                acc3b[m][n] = __builtin_amdgcn_mfma_f32_16x16x16f16(af3[m][kc], bf[n], acc3b[m][n], 0, 0, 0);
    }
    __syncthreads();

    // ---- flush hsL -> hs, h1L -> ssrc (coalesced 16B) ----
    #pragma unroll
    for (int i = 0; i < 8; ++i) {
        int q = t + i * 256;               // 2048 chunks of 8 f16
        int hd = q >> 9, row = (q >> 3) & 63, c8 = (q & 7) << 3;
        int node = base + row;
        if (node < NN) {
            *(int4*)&hs[(size_t)node * HF + hd * EM + c8]   = *(int4*)&hsL[hd][row][c8];
            *(int4*)&ssrc[(size_t)node * HF + hd * EM + c8] = *(int4*)&h1L[hd][row][c8];
        }
    }
    __syncthreads();

    // ---- write acc3b -> hsL, flush -> sdst ----
    #pragma unroll
    for (int n = 0; n < 4; ++n)
        #pragma unroll
        for (int m = 0; m < 4; ++m)
            #pragma unroll
            for (int r = 0; r < 4; ++r)
                hsL[h][m * 16 + 4 * g + r][n * 16 + c] = (f16)acc3b[m][n][r];
    __syncthreads();
    #pragma unroll
    for (int i = 0; i < 8; ++i) {
        int q = t + i * 256;
        int hd = q >> 9, row = (q >> 3) & 63, c8 = (q & 7) << 3;
        int node = base + row;
        if (node < NN)
            *(int4*)&sdst[(size_t)node * HF + hd * EM + c8] = *(int4*)&hsL[hd][row][c8];
    }
}

// ---------------- CSR build ----------------
__global__ __launch_bounds__(256) void k_deg(const int* __restrict__ idx, int* __restrict__ cnt)
{
    int e = blockIdx.x * 256 + threadIdx.x;
    atomicAdd(cnt + idx[e], 1);
}

__global__ __launch_bounds__(256) void k_scan1(const int* __restrict__ arr, int* __restrict__ bsum)
{
    const int t = threadIdx.x, lane = t & 63, w = t >> 6;
    int i = blockIdx.x * 256 + t;
    int v = (i < NN) ? arr[i] : 0;
    #pragma unroll
    for (int d = 1; d < 64; d <<= 1) v += __shfl_xor(v, d);
    __shared__ int ws[4];
    if (lane == 0) ws[w] = v;
    __syncthreads();
    if (t == 0) bsum[blockIdx.x] = ws[0] + ws[1] + ws[2] + ws[3];
}

__global__ __launch_bounds__(256) void k_scan2(int* __restrict__ bsum)
{
    __shared__ int wsum[4], woff[4];
    __shared__ int base, ctot;
    const int t = threadIdx.x, lane = t & 63, w = t >> 6;
    if (t == 0) base = 0;
    __syncthreads();
    for (int start = 0; start < NB_SCAN; start += 256) {
        int i = start + t;
        int v = (i < NB_SCAN) ? bsum[i] : 0;
        int incl = v;
        #pragma unroll
        for (int d = 1; d < 64; d <<= 1) {
            int u = __shfl_up(incl, d);
            if (lane >= d) incl += u;
        }
        if (lane == 63) wsum[w] = incl;
        __syncthreads();
        if (t == 0) {
            int s = 0;
            #pragma unroll
            for (int j = 0; j < 4; ++j) { int xv = wsum[j]; woff[j] = s; s += xv; }
            ctot = s;
        }
        __syncthreads();
        if (i < NB_SCAN) bsum[i] = base + woff[w] + incl - v;
        __syncthreads();
        if (t == 0) base += ctot;
        __syncthreads();
    }
}

__global__ __launch_bounds__(256) void k_scan3(int* __restrict__ arr, const int* __restrict__ bsum)
{
    const int t = threadIdx.x, lane = t & 63, w = t >> 6;
    int i = blockIdx.x * 256 + t;
    int v = (i < NN) ? arr[i] : 0;
    int incl = v;
    #pragma unroll
    for (int d = 1; d < 64; d <<= 1) {
        int u = __shfl_up(incl, d);
        if (lane >= d) incl += u;
    }
    __shared__ int wsum[4], woff[4];
    if (lane == 63) wsum[w] = incl;
    __syncthreads();
    if (t == 0) {
        int s = 0;
        #pragma unroll
        for (int j = 0; j < 4; ++j) { int xv = wsum[j]; woff[j] = s; s += xv; }
    }
    __syncthreads();
    if (i < NN) arr[i] = bsum[blockIdx.x] + woff[w] + incl - v;
}

__global__ __launch_bounds__(256) void k_fill(const int* __restrict__ idx,
                                              int* __restrict__ cur, int* __restrict__ lst)
{
    int e = blockIdx.x * 256 + threadIdx.x;
    int pos = atomicAdd(cur + idx[e], 1);
    lst[pos] = e;
}

// ---------------- Pass A: src-CSR attention + in-place hs normalize ----------------
__global__ __launch_bounds__(256) void k_edge_att_csr(
    const int* __restrict__ ei, const int* __restrict__ es, const int* __restrict__ cur_s,
    const __half* __restrict__ ssrc, const __half* __restrict__ sdst,
    const float* __restrict__ ba1, const float* __restrict__ Wa2, const float* __restrict__ ba2,
    __half* __restrict__ eatt, __half* __restrict__ hs)
{
    const int wave = threadIdx.x >> 6;
    const int lane = threadIdx.x & 63;
    const int n = blockIdx.x * 4 + wave;
    const int h = lane >> 4;
    const int kq = lane & 15;

    const int beg = (n == 0) ? 0 : cur_s[n - 1];
    const int end = cur_s[n];
    if (beg >= end) return;

    const float4 ba1v = *(const float4*)(ba1 + h * EM + kq * 4);
    const float4 w2v  = *(const float4*)(Wa2 + h * EM + kq * 4);
    const float  ba2v = ba2[h];

    H4 sv = ((const H4*)(ssrc + (size_t)n * HF))[lane];
    float2 s0 = __half22float2(sv.a), s1 = __half22float2(sv.b);
    const float z0 = s0.x + ba1v.x, z1 = s0.y + ba1v.y;
    const float z2 = s1.x + ba1v.z, z3 = s1.y + ba1v.w;

    float esum = 0.f;
    int p = beg;
    int e_n = es[p];
    int d_n = ei[NE + e_n];
    while (p < end) {
        const int e = e_n, dst = d_n;
        if (p + 1 < end) { e_n = es[p + 1]; d_n = ei[NE + e_n]; }

        H4 dv = ((const H4*)(sdst + (size_t)dst * HF))[lane];
        float2 d0 = __half22float2(dv.a), d1 = __half22float2(dv.b);
        float t0 = lrelu(z0 + d0.x), t1 = lrelu(z1 + d0.y);
        float t2 = lrelu(z2 + d1.x), t3 = lrelu(z3 + d1.y);
        float pv = fmaf(t0, w2v.x, fmaf(t1, w2v.y, fmaf(t2, w2v.z, t3 * w2v.w)));
        pv += __shfl_xor(pv, 1);
        pv += __shfl_xor(pv, 2);
        pv += __shfl_xor(pv, 4);
        pv += __shfl_xor(pv, 8);
        float a = lrelu(pv + ba2v);
        float eh = __expf(a);
        esum += eh;
        if (kq == 0) eatt[(size_t)e * HEADS + h] = __float2half_rn(eh);
        ++p;
    }

    float inv = 1.f / esum;
    H4* hrow = (H4*)(hs + (size_t)n * HF);
    H4 hv = hrow[lane];
    float2 h0 = __half22float2(hv.a), h1 = __half22float2(hv.b);
    H4 o;
    o.a = __floats2half2_rn(h0.x * inv, h0.y * inv);
    o.b = __floats2half2_rn(h1.x * inv, h1.y * inv);
    hrow[lane] = o;
}

// ---------------- Pass B: dst-CSR gather aggregation ----------------
__global__ __launch_bounds__(256) void k_aggregate_csr(
    const int* __restrict__ ei, const int* __restrict__ ed, const int* __restrict__ cur_d,
    const __half* __restrict__ hs, const __half* __restrict__ eatt,
    __half* __restrict__ agg)
{
    const int wave = threadIdx.x >> 6;
    const int lane = threadIdx.x & 63;
    const int n = blockIdx.x * 4 + wave;
    const int h = lane >> 4;

    const int beg = (n == 0) ? 0 : cur_d[n - 1];
    const int end = cur_d[n];
    float a0 = 0.f, a1 = 0.f, a2 = 0.f, a3 = 0.f;

    int p = beg;
    int e_n = 0, s_n = 0;
    if (p < end) { e_n = ed[p]; s_n = ei[e_n]; }
    while (p < end) {
        const int e = e_n, src = s_n;
        if (p + 1 < end) { e_n = ed[p + 1]; s_n = ei[e_n]; }

        float al = __half2float(eatt[(size_t)e * HEADS + h]);
        H4 hv = ((const H4*)(hs + (size_t)src * HF))[lane];
        float2 h0 = __half22float2(hv.a), h1 = __half22float2(hv.b);
        a0 = fmaf(h0.x, al, a0);
        a1 = fmaf(h0.y, al, a1);
        a2 = fmaf(h1.x, al, a2);
        a3 = fmaf(h1.y, al, a3);
        ++p;
    }
    H4 o;
    o.a = __floats2half2_rn(a0, a1);
    o.b = __floats2half2_rn(a2, a3);
    ((H4*)(agg + (size_t)n * HF))[lane] = o;
}

// =====================================================================
// k_out_mlp2: out = lrelu(agg * Wf1 + bf1) * Wf2 + bf2, MFMA.
// Block = 64 nodes, 4 waves. GEMM-a: wave w owns cols w*16..w*16+16 of mid.
// GEMM-b: wave w owns cols {w,w+4}*16 of out.
// =====================================================================
__global__ __launch_bounds__(256) void k_out_mlp2(
    const f16* __restrict__ agg,
    const float* __restrict__ Wf1, const float* __restrict__ bf1,
    const float* __restrict__ Wf2, const float* __restrict__ bf2,
    float* __restrict__ out)
{
    __shared__ __align__(16) f16 aggL[64][272];   // 34.8KB
    __shared__ __align__(16) f16 midL[64][72];    // 9.2KB

    const int t = threadIdx.x;
    const int base = blockIdx.x * 64;

    #pragma unroll
    for (int i = 0; i < 8; ++i) {
        int q = t + i * 256;               // 2048 chunks of 8 f16
        int row = q >> 5, c8 = (q & 31) << 3;
        int gr = base + row; if (gr >= NN) gr = NN - 1;
        *(int4*)&aggL[row][c8] = *(const int4*)&agg[(size_t)gr * HF + c8];
    }
    __syncthreads();

    const int w = t >> 6, l = t & 63;
    const int g = l >> 4, c = l & 15;
    const f32x4 z4 = { 0.f, 0.f, 0.f, 0.f };

    // GEMM-a: mid = lrelu(agg * Wf1 + bf1), K=256
    {
        f32x4 acc[4] = { z4, z4, z4, z4 };
        for (int kc = 0; kc < 16; ++kc) {
            const float* wp = Wf1 + (size_t)(kc * 16 + 4 * g) * HI + w * 16 + c;
            f16x4 bf;
            bf[0] = (f16)wp[0]; bf[1] = (f16)wp[HI]; bf[2] = (f16)wp[2 * HI]; bf[3] = (f16)wp[3 * HI];
            #pragma unroll
            for (int m = 0; m < 4; ++m) {
                f16x4 af = *(const f16x4*)&aggL[m * 16 + c][kc * 16 + 4 * g];
                acc[m] = __builtin_amdgcn_mfma_f32_16x16x16f16(af, bf, acc[m], 0, 0, 0);
            }
        }
        float b = bf1[w * 16 + c];
        #pragma unroll
        for (int m = 0; m < 4; ++m)
            #pragma unroll
            for (int r = 0; r < 4; ++r)
                midL[m * 16 + 4 * g + r][w * 16 + c] = (f16)lrelu(acc[m][r] + b);
    }
    __syncthreads();

    // GEMM-b: out = mid * Wf2 + bf2, K=64, N=128
    #pragma unroll
    for (int nb = 0; nb < 2; ++nb) {
        int nt = w + nb * 4;
        f32x4 acc[4] = { z4, z4, z4, z4 };
        for (int kc = 0; kc < 4; ++kc) {
            const float* wp = Wf2 + (size_t)(kc * 16 + 4 * g) * OUT_DIM + nt * 16 + c;
            f16x4 bf;
            bf[0] = (f16)wp[0]; bf[1] = (f16)wp[OUT_DIM]; bf[2] = (f16)wp[2 * OUT_DIM]; bf[3] = (f16)wp[3 * OUT_DIM];
            #pragma unroll
            for (int m = 0; m < 4; ++m) {
                f16x4 af = *(const f16x4*)&midL[m * 16 + c][kc * 16 + 4 * g];
                acc[m] = __builtin_amdgcn_mfma_f32_16x16x16f16(af, bf, acc[m], 0, 0, 0);
            }
        }
        float b = bf2[nt * 16 + c];
        #pragma unroll
        for (int m = 0; m < 4; ++m)
            #pragma unroll
            for (int r = 0; r < 4; ++r) {
                int node = base + m * 16 + 4 * g + r;
                if (node < NN) out[(size_t)node * OUT_DIM + nt * 16 + c] = acc[m][r] + b;
            }
    }
}

extern "C" void kernel_launch(void* const* d_in, const int* in_sizes, int n_in,
                              void* d_out, int out_size, void* d_ws, size_t ws_size,
                              hipStream_t stream) {
    const float* x   = (const float*)d_in[0];
    const int*   ei  = (const int*)d_in[1];
    const float* Wi1 = (const float*)d_in[2];
    const float* bi1 = (const float*)d_in[3];
    const float* Wi2 = (const float*)d_in[4];
    const float* bi2 = (const float*)d_in[5];
    const float* Wa1 = (const float*)d_in[6];
    const float* ba1 = (const float*)d_in[7];
    const float* Wa2 = (const float*)d_in[8];
    const float* ba2 = (const float*)d_in[9];
    const float* Wf1 = (const float*)d_in[10];
    const float* bf1 = (const float*)d_in[11];
    const float* Wf2 = (const float*)d_in[12];
    const float* bf2 = (const float*)d_in[13];
    float* out = (float*)d_out;

    const size_t HS_B = (size_t)NN * HF * sizeof(__half);      // 51.2e6
    const size_t OFF_SSRC = HS_B;
    const size_t OFF_SDST = 2 * HS_B;
    const size_t OFF_EATT = 3 * HS_B;
    const size_t OFF_CURS = OFF_EATT + (size_t)NE * HEADS * sizeof(__half);
    const size_t OFF_CURD = OFF_CURS + (size_t)NN * sizeof(int);
    const size_t OFF_BSUM = OFF_CURD + (size_t)NN * sizeof(int);
    const size_t OFF_ES   = OFF_BSUM + 4096;
    const size_t NEED     = OFF_ES + (size_t)NE * sizeof(int); // ~173.6 MB
    if (ws_size < NEED) return;

    char* ws = (char*)d_ws;
    f16*    hs   = (f16*)(ws);
    f16*    ssrc = (f16*)(ws + OFF_SSRC);
    f16*    sdst = (f16*)(ws + OFF_SDST);
    __half* eatt = (__half*)(ws + OFF_EATT);
    int* cur_s   = (int*)(ws + OFF_CURS);
    int* cur_d   = (int*)(ws + OFF_CURD);
    int* bsum    = (int*)(ws + OFF_BSUM);
    int* es      = (int*)(ws + OFF_ES);
    f16*    agg  = (f16*)(ws + OFF_SSRC);      // aliases ssrc (dead after pass A)
    int* ed      = (int*)(ws + OFF_SDST);      // aliases sdst (dead after pass A)

    const int NB64 = (NN + 63) / 64;           // 1563

    k_embed<<<NB64, 256, 0, stream>>>(x, Wi1, bi1, Wi2, bi2, Wa1, hs, ssrc, sdst);

    // src-CSR
    hipMemsetAsync(cur_s, 0, (size_t)NN * sizeof(int), stream);
    k_deg<<<NE / 256, 256, 0, stream>>>(ei, cur_s);
    k_scan1<<<NB_SCAN, 256, 0, stream>>>(cur_s, bsum);
    k_scan2<<<1, 256, 0, stream>>>(bsum);
    k_scan3<<<NB_SCAN, 256, 0, stream>>>(cur_s, bsum);
    k_fill<<<NE / 256, 256, 0, stream>>>(ei, cur_s, es);

    // pass A
    k_edge_att_csr<<<NN / 4, 256, 0, stream>>>(ei, es, cur_s,
        (const __half*)ssrc, (const __half*)sdst, ba1, Wa2, ba2, eatt, (__half*)hs);

    // dst-CSR (into dead sdst region)
    hipMemsetAsync(cur_d, 0, (size_t)NN * sizeof(int), stream);
    k_deg<<<NE / 256, 256, 0, stream>>>(ei + NE, cur_d);
    k_scan1<<<NB_SCAN, 256, 0, stream>>>(cur_d, bsum);
    k_scan2<<<1, 256, 0, stream>>>(bsum);
    k_scan3<<<NB_SCAN, 256, 0, stream>>>(cur_d, bsum);
    k_fill<<<NE / 256, 256, 0, stream>>>(ei + NE, cur_d, ed);

    // pass B
    k_aggregate_csr<<<NN / 4, 256, 0, stream>>>(ei, ed, cur_d,
        (const __half*)hs, (const __half*)eatt, (__half*)agg);

    k_out_mlp2<<<NB64, 256, 0, stream>>>(agg, Wf1, bf1, Wf2, bf2, out);
}

// Round 7
// 868.123 us; speedup vs baseline: 7.1207x; 1.1560x over previous
//
#include <hip/hip_runtime.h>
#include <hip/hip_fp16.h>

#define NN 100000
#define NE 1600000
#define HEADS 4
#define EM 64
#define HF 256      // HEADS*EM
#define IN_DIM 128
#define HI 64
#define OUT_DIM 128
#define NB_SCAN 391  // ceil(NN/256)

using f16 = _Float16;
typedef _Float16 f16x2 __attribute__((ext_vector_type(2)));
typedef _Float16 f16x4 __attribute__((ext_vector_type(4)));
typedef float f32x4 __attribute__((ext_vector_type(4)));

__device__ __forceinline__ float lrelu(float x) { return fmaxf(x, 0.01f * x); }

// =====================================================================
// k_embed: fused node MLP + attention projections, MFMA 16x16x16 f16.
// (unchanged from round 4 — verified)
// =====================================================================
__global__ __launch_bounds__(256) void k_embed(
    const float* __restrict__ x,
    const float* __restrict__ Wi1, const float* __restrict__ bi1,
    const float* __restrict__ Wi2, const float* __restrict__ bi2,
    const float* __restrict__ Wa1,
    f16* __restrict__ hs, f16* __restrict__ ssrc, f16* __restrict__ sdst)
{
    __shared__ __align__(16) char smem[73728];
    f16 (*xh)[136]      = (f16(*)[136])smem;
    f16 (*hsL)[64][72]  = (f16(*)[64][72])smem;
    f16 (*h1L)[64][72]  = (f16(*)[64][72])(smem + 36864);

    const int t = threadIdx.x;
    const int base = blockIdx.x * 64;

    #pragma unroll
    for (int i = 0; i < 8; ++i) {
        int q = t + i * 256;
        int row = q >> 5;
        int c4 = (q & 31) << 2;
        int gr = base + row; if (gr >= NN) gr = NN - 1;
        float4 v = *(const float4*)(x + (size_t)gr * IN_DIM + c4);
        f16x4 hv = { (f16)v.x, (f16)v.y, (f16)v.z, (f16)v.w };
        *(f16x4*)&xh[row][c4] = hv;
    }
    __syncthreads();

    const int h = t >> 6;
    const int l = t & 63;
    const int g = l >> 4;
    const int c = l & 15;

    const f32x4 z4 = { 0.f, 0.f, 0.f, 0.f };

    f32x4 acc1[4][4];
    #pragma unroll
    for (int m = 0; m < 4; ++m)
        #pragma unroll
        for (int n = 0; n < 4; ++n) acc1[m][n] = z4;

    {
        const float* W = Wi1 + (size_t)h * IN_DIM * EM;
        for (int kc = 0; kc < 8; ++kc) {
            f16x4 bf[4];
            #pragma unroll
            for (int n = 0; n < 4; ++n) {
                const float* wp = W + (size_t)(kc * 16 + 4 * g) * EM + n * 16 + c;
                f16x4 b;
                b[0] = (f16)wp[0]; b[1] = (f16)wp[EM]; b[2] = (f16)wp[2 * EM]; b[3] = (f16)wp[3 * EM];
                bf[n] = b;
            }
            #pragma unroll
            for (int m = 0; m < 4; ++m) {
                f16x4 af = *(const f16x4*)&xh[m * 16 + c][kc * 16 + 4 * g];
                #pragma unroll
                for (int n = 0; n < 4; ++n)
                    acc1[m][n] = __builtin_amdgcn_mfma_f32_16x16x16f16(af, bf[n], acc1[m][n], 0, 0, 0);
            }
        }
    }
    __syncthreads();

    #pragma unroll
    for (int n = 0; n < 4; ++n) {
        float b = bi1[h * EM + n * 16 + c];
        #pragma unroll
        for (int m = 0; m < 4; ++m)
            #pragma unroll
            for (int r = 0; r < 4; ++r)
                h1L[h][m * 16 + 4 * g + r][n * 16 + c] = (f16)lrelu(acc1[m][n][r] + b);
    }
    __syncthreads();

    f32x4 acc2[4][4];
    #pragma unroll
    for (int m = 0; m < 4; ++m)
        #pragma unroll
        for (int n = 0; n < 4; ++n) acc2[m][n] = z4;
    {
        const float* W = Wi2 + (size_t)h * EM * EM;
        for (int kc = 0; kc < 4; ++kc) {
            f16x4 bf[4];
            #pragma unroll
            for (int n = 0; n < 4; ++n) {
                const float* wp = W + (size_t)(kc * 16 + 4 * g) * EM + n * 16 + c;
                f16x4 b;
                b[0] = (f16)wp[0]; b[1] = (f16)wp[EM]; b[2] = (f16)wp[2 * EM]; b[3] = (f16)wp[3 * EM];
                bf[n] = b;
            }
            #pragma unroll
            for (int m = 0; m < 4; ++m) {
                f16x4 af = *(const f16x4*)&h1L[h][m * 16 + c][kc * 16 + 4 * g];
                #pragma unroll
                for (int n = 0; n < 4; ++n)
                    acc2[m][n] = __builtin_amdgcn_mfma_f32_16x16x16f16(af, bf[n], acc2[m][n], 0, 0, 0);
            }
        }
    }
    #pragma unroll
    for (int n = 0; n < 4; ++n) {
        float b = bi2[h * EM + n * 16 + c];
        #pragma unroll
        for (int m = 0; m < 4; ++m)
            #pragma unroll
            for (int r = 0; r < 4; ++r)
                hsL[h][m * 16 + 4 * g + r][n * 16 + c] = (f16)(acc2[m][n][r] + b);
    }
    __syncthreads();

    f16x4 af3[4][4];
    #pragma unroll
    for (int m = 0; m < 4; ++m)
        #pragma unroll
        for (int kc = 0; kc < 4; ++kc)
            af3[m][kc] = *(const f16x4*)&hsL[h][m * 16 + c][kc * 16 + 4 * g];

    const float* Wa = Wa1 + (size_t)h * (2 * EM) * HI;
    {
        f32x4 acc3[4][4];
        #pragma unroll
        for (int m = 0; m < 4; ++m)
            #pragma unroll
            for (int n = 0; n < 4; ++n) acc3[m][n] = z4;
        for (int kc = 0; kc < 4; ++kc) {
            f16x4 bf[4];
            #pragma unroll
            for (int n = 0; n < 4; ++n) {
                const float* wp = Wa + (size_t)(kc * 16 + 4 * g) * HI + n * 16 + c;
                f16x4 b;
                b[0] = (f16)wp[0]; b[1] = (f16)wp[HI]; b[2] = (f16)wp[2 * HI]; b[3] = (f16)wp[3 * HI];
                bf[n] = b;
            }
            #pragma unroll
            for (int m = 0; m < 4; ++m)
                #pragma unroll
                for (int n = 0; n < 4; ++n)
                    acc3[m][n] = __builtin_amdgcn_mfma_f32_16x16x16f16(af3[m][kc], bf[n], acc3[m][n], 0, 0, 0);
        }
        #pragma unroll
        for (int n = 0; n < 4; ++n)
            #pragma unroll
            for (int m = 0; m < 4; ++m)
                #pragma unroll
                for (int r = 0; r < 4; ++r)
                    h1L[h][m * 16 + 4 * g + r][n * 16 + c] = (f16)acc3[m][n][r];
    }
    f32x4 acc3b[4][4];
    #pragma unroll
    for (int m = 0; m < 4; ++m)
        #pragma unroll
        for (int n = 0; n < 4; ++n) acc3b[m][n] = z4;
    for (int kc = 0; kc < 4; ++kc) {
        f16x4 bf[4];
        #pragma unroll
        for (int n = 0; n < 4; ++n) {
            const float* wp = Wa + (size_t)(EM + kc * 16 + 4 * g) * HI + n * 16 + c;
            f16x4 b;
            b[0] = (f16)wp[0]; b[1] = (f16)wp[HI]; b[2] = (f16)wp[2 * HI]; b[3] = (f16)wp[3 * HI];
            bf[n] = b;
        }
        #pragma unroll
        for (int m = 0; m < 4; ++m)
            #pragma unroll
            for (int n = 0; n < 4; ++n)
                acc3b[m][n] = __builtin_amdgcn_mfma_f32_16x16x16f16(af3[m][kc], bf[n], acc3b[m][n], 0, 0, 0);
    }
    __syncthreads();

    #pragma unroll
    for (int i = 0; i < 8; ++i) {
        int q = t + i * 256;
        int hd = q >> 9, row = (q >> 3) & 63, c8 = (q & 7) << 3;
        int node = base + row;
        if (node < NN) {
            *(int4*)&hs[(size_t)node * HF + hd * EM + c8]   = *(int4*)&hsL[hd][row][c8];
            *(int4*)&ssrc[(size_t)node * HF + hd * EM + c8] = *(int4*)&h1L[hd][row][c8];
        }
    }
    __syncthreads();

    #pragma unroll
    for (int n = 0; n < 4; ++n)
        #pragma unroll
        for (int m = 0; m < 4; ++m)
            #pragma unroll
            for (int r = 0; r < 4; ++r)
                hsL[h][m * 16 + 4 * g + r][n * 16 + c] = (f16)acc3b[m][n][r];
    __syncthreads();
    #pragma unroll
    for (int i = 0; i < 8; ++i) {
        int q = t + i * 256;
        int hd = q >> 9, row = (q >> 3) & 63, c8 = (q & 7) << 3;
        int node = base + row;
        if (node < NN)
            *(int4*)&sdst[(size_t)node * HF + hd * EM + c8] = *(int4*)&hsL[hd][row][c8];
    }
}

// ---------------- CSR build ----------------
__global__ __launch_bounds__(256) void k_deg2(const int* __restrict__ ei,
                                              int* __restrict__ cs, int* __restrict__ cd)
{
    int e = blockIdx.x * 256 + threadIdx.x;
    atomicAdd(cs + ei[e], 1);
    atomicAdd(cd + ei[NE + e], 1);
}

__global__ __launch_bounds__(256) void k_scan1(const int* __restrict__ arr, int* __restrict__ bsum)
{
    const int t = threadIdx.x, lane = t & 63, w = t >> 6;
    int i = blockIdx.x * 256 + t;
    int v = (i < NN) ? arr[i] : 0;
    #pragma unroll
    for (int d = 1; d < 64; d <<= 1) v += __shfl_xor(v, d);
    __shared__ int ws[4];
    if (lane == 0) ws[w] = v;
    __syncthreads();
    if (t == 0) bsum[blockIdx.x] = ws[0] + ws[1] + ws[2] + ws[3];
}

__global__ __launch_bounds__(256) void k_scan2(int* __restrict__ bsum)
{
    __shared__ int wsum[4], woff[4];
    __shared__ int base, ctot;
    const int t = threadIdx.x, lane = t & 63, w = t >> 6;
    if (t == 0) base = 0;
    __syncthreads();
    for (int start = 0; start < NB_SCAN; start += 256) {
        int i = start + t;
        int v = (i < NB_SCAN) ? bsum[i] : 0;
        int incl = v;
        #pragma unroll
        for (int d = 1; d < 64; d <<= 1) {
            int u = __shfl_up(incl, d);
            if (lane >= d) incl += u;
        }
        if (lane == 63) wsum[w] = incl;
        __syncthreads();
        if (t == 0) {
            int s = 0;
            #pragma unroll
            for (int j = 0; j < 4; ++j) { int xv = wsum[j]; woff[j] = s; s += xv; }
            ctot = s;
        }
        __syncthreads();
        if (i < NB_SCAN) bsum[i] = base + woff[w] + incl - v;
        __syncthreads();
        if (t == 0) base += ctot;
        __syncthreads();
    }
}

__global__ __launch_bounds__(256) void k_scan3(int* __restrict__ arr, const int* __restrict__ bsum)
{
    const int t = threadIdx.x, lane = t & 63, w = t >> 6;
    int i = blockIdx.x * 256 + t;
    int v = (i < NN) ? arr[i] : 0;
    int incl = v;
    #pragma unroll
    for (int d = 1; d < 64; d <<= 1) {
        int u = __shfl_up(incl, d);
        if (lane >= d) incl += u;
    }
    __shared__ int wsum[4], woff[4];
    if (lane == 63) wsum[w] = incl;
    __syncthreads();
    if (t == 0) {
        int s = 0;
        #pragma unroll
        for (int j = 0; j < 4; ++j) { int xv = wsum[j]; woff[j] = s; s += xv; }
    }
    __syncthreads();
    if (i < NN) arr[i] = bsum[blockIdx.x] + woff[w] + incl - v;
}

// fill src list: es2[pos] = {dst, e}
__global__ __launch_bounds__(256) void k_fill_src(const int* __restrict__ ei,
                                                  int* __restrict__ cur, int2* __restrict__ es2)
{
    int e = blockIdx.x * 256 + threadIdx.x;
    int src = ei[e], dst = ei[NE + e];
    int pos = atomicAdd(cur + src, 1);
    es2[pos] = make_int2(dst, e);
}

// fill dst list: ed2[pos] = {src, e}
__global__ __launch_bounds__(256) void k_fill_dst(const int* __restrict__ ei,
                                                  int* __restrict__ cur, int2* __restrict__ ed2)
{
    int e = blockIdx.x * 256 + threadIdx.x;
    int src = ei[e], dst = ei[NE + e];
    int pos = atomicAdd(cur + dst, 1);
    ed2[pos] = make_int2(src, e);
}

// ---------------- Pass A: src-CSR attention, packed f16, unroll-2 pipeline ----------------
__global__ __launch_bounds__(256) void k_edge_att_csr(
    const int2* __restrict__ es2, const int* __restrict__ cur_s,
    const f16* __restrict__ ssrc, const f16* __restrict__ sdst,
    const float* __restrict__ ba1, const float* __restrict__ Wa2, const float* __restrict__ ba2,
    f16* __restrict__ eatt, f16* __restrict__ hs)
{
    const int wave = threadIdx.x >> 6;
    const int lane = threadIdx.x & 63;
    const int n = blockIdx.x * 4 + wave;
    const int h = lane >> 4;
    const int kq = lane & 15;

    const int beg = (n == 0) ? 0 : cur_s[n - 1];
    const int end = cur_s[n];
    if (beg >= end) return;

    const float4 ba1v = *(const float4*)(ba1 + h * EM + kq * 4);
    const float4 w2v  = *(const float4*)(Wa2 + h * EM + kq * 4);
    const float  ba2v = ba2[h];
    const f16x2 w01 = { (f16)w2v.x, (f16)w2v.y };
    const f16x2 w23 = { (f16)w2v.z, (f16)w2v.w };
    const f16x2 c001 = { (f16)0.01f, (f16)0.01f };

    const uint2* sd8 = (const uint2*)sdst;   // 8B units; row n -> n*64 + lane

    uint2 sv = ((const uint2*)(ssrc + (size_t)n * HF))[lane];
    const f16x2 z01 = *(f16x2*)&sv.x + (f16x2){ (f16)ba1v.x, (f16)ba1v.y };
    const f16x2 z23 = *(f16x2*)&sv.y + (f16x2){ (f16)ba1v.z, (f16)ba1v.w };

    float esum = 0.f;

#define COMP_A(eV, dV)                                                          \
    {                                                                           \
        f16x2 u01 = z01 + *(f16x2*)&dV.x;                                       \
        f16x2 u23 = z23 + *(f16x2*)&dV.y;                                       \
        u01 = __builtin_elementwise_max(u01, u01 * c001);                       \
        u23 = __builtin_elementwise_max(u23, u23 * c001);                       \
        f16x2 pr = u01 * w01 + u23 * w23;                                       \
        float pv = (float)pr.x + (float)pr.y;                                   \
        pv += __shfl_xor(pv, 1);                                                \
        pv += __shfl_xor(pv, 2);                                                \
        pv += __shfl_xor(pv, 4);                                                \
        pv += __shfl_xor(pv, 8);                                                \
        float a = pv + ba2v; a = fmaxf(a, 0.01f * a);                           \
        float eh = __expf(a);                                                   \
        esum += eh;                                                             \
        if (kq == 0) eatt[(size_t)eV.y * 4 + h] = (f16)eh;                      \
    }

    int p = beg;
    int2 eA = es2[p];
    uint2 dvA = sd8[(size_t)eA.x * 64 + lane];
    int2 eB = eA; uint2 dvB = make_uint2(0, 0);
    if (p + 1 < end) { eB = es2[p + 1]; dvB = sd8[(size_t)eB.x * 64 + lane]; }

    while (p + 1 < end) {
        int2 nA = eA, nB = eB;
        uint2 pfA = make_uint2(0, 0), pfB = make_uint2(0, 0);
        if (p + 2 < end) { nA = es2[p + 2]; pfA = sd8[(size_t)nA.x * 64 + lane]; }
        if (p + 3 < end) { nB = es2[p + 3]; pfB = sd8[(size_t)nB.x * 64 + lane]; }
        COMP_A(eA, dvA);
        COMP_A(eB, dvB);
        eA = nA; dvA = pfA; eB = nB; dvB = pfB;
        p += 2;
    }
    if (p < end) COMP_A(eA, dvA);
#undef COMP_A

    // fold 1/esum into hs (row owned by this wave)
    float inv = 1.f / esum;
    uint2* hrow = (uint2*)(hs + (size_t)n * HF);
    uint2 hv = hrow[lane];
    f16x2 h0 = *(f16x2*)&hv.x, h1 = *(f16x2*)&hv.y;
    uint2 o;
    f16x2 r0 = { (f16)((float)h0.x * inv), (f16)((float)h0.y * inv) };
    f16x2 r1 = { (f16)((float)h1.x * inv), (f16)((float)h1.y * inv) };
    *(f16x2*)&o.x = r0;
    *(f16x2*)&o.y = r1;
    hrow[lane] = o;
}

// ---------------- Pass B: dst-CSR gather aggregation, unroll-2 pipeline ----------------
__global__ __launch_bounds__(256) void k_aggregate_csr(
    const int2* __restrict__ ed2, const int* __restrict__ cur_d,
    const f16* __restrict__ hs, const f16* __restrict__ eatt,
    f16* __restrict__ agg)
{
    const int wave = threadIdx.x >> 6;
    const int lane = threadIdx.x & 63;
    const int n = blockIdx.x * 4 + wave;
    const int h = lane >> 4;

    const int beg = (n == 0) ? 0 : cur_d[n - 1];
    const int end = cur_d[n];

    const uint2* hs8 = (const uint2*)hs;     // 8B units
    const uint2* at8 = (const uint2*)eatt;   // eatt[e] = 4 halves = 8B

    float a0 = 0.f, a1 = 0.f, a2 = 0.f, a3 = 0.f;

#define COMP_B(atV, hV)                                                         \
    {                                                                           \
        uint sel = (h & 2) ? atV.y : atV.x;                                     \
        f16x2 selh = *(f16x2*)&sel;                                             \
        float al = (float)((h & 1) ? selh.y : selh.x);                          \
        f16x2 f01 = *(f16x2*)&hV.x;                                             \
        f16x2 f23 = *(f16x2*)&hV.y;                                             \
        a0 = fmaf((float)f01.x, al, a0); a1 = fmaf((float)f01.y, al, a1);       \
        a2 = fmaf((float)f23.x, al, a2); a3 = fmaf((float)f23.y, al, a3);       \
    }

    int p = beg;
    if (p < end) {
        int2 sA = ed2[p];
        uint2 atA = at8[sA.y];
        uint2 hvA = hs8[(size_t)sA.x * 64 + lane];
        int2 sB; uint2 atB = make_uint2(0, 0), hvB = make_uint2(0, 0);
        if (p + 1 < end) {
            sB = ed2[p + 1];
            atB = at8[sB.y];
            hvB = hs8[(size_t)sB.x * 64 + lane];
        }
        while (p + 1 < end) {
            uint2 pfAt = make_uint2(0, 0), pfHv = make_uint2(0, 0);
            uint2 pfAt2 = make_uint2(0, 0), pfHv2 = make_uint2(0, 0);
            if (p + 2 < end) {
                int2 nA = ed2[p + 2];
                pfAt = at8[nA.y];
                pfHv = hs8[(size_t)nA.x * 64 + lane];
            }
            if (p + 3 < end) {
                int2 nB = ed2[p + 3];
                pfAt2 = at8[nB.y];
                pfHv2 = hs8[(size_t)nB.x * 64 + lane];
            }
            COMP_B(atA, hvA);
            COMP_B(atB, hvB);
            atA = pfAt; hvA = pfHv; atB = pfAt2; hvB = pfHv2;
            p += 2;
        }
        if (p < end) COMP_B(atA, hvA);
    }
#undef COMP_B

    uint2 o;
    f16x2 r0 = { (f16)a0, (f16)a1 };
    f16x2 r1 = { (f16)a2, (f16)a3 };
    *(f16x2*)&o.x = r0;
    *(f16x2*)&o.y = r1;
    ((uint2*)(agg + (size_t)n * HF))[lane] = o;
}

// =====================================================================
// k_out_mlp2 (unchanged from round 4 — verified)
// =====================================================================
__global__ __launch_bounds__(256) void k_out_mlp2(
    const f16* __restrict__ agg,
    const float* __restrict__ Wf1, const float* __restrict__ bf1,
    const float* __restrict__ Wf2, const float* __restrict__ bf2,
    float* __restrict__ out)
{
    __shared__ __align__(16) f16 aggL[64][272];
    __shared__ __align__(16) f16 midL[64][72];

    const int t = threadIdx.x;
    const int base = blockIdx.x * 64;

    #pragma unroll
    for (int i = 0; i < 8; ++i) {
        int q = t + i * 256;
        int row = q >> 5, c8 = (q & 31) << 3;
        int gr = base + row; if (gr >= NN) gr = NN - 1;
        *(int4*)&aggL[row][c8] = *(const int4*)&agg[(size_t)gr * HF + c8];
    }
    __syncthreads();

    const int w = t >> 6, l = t & 63;
    const int g = l >> 4, c = l & 15;
    const f32x4 z4 = { 0.f, 0.f, 0.f, 0.f };

    {
        f32x4 acc[4] = { z4, z4, z4, z4 };
        for (int kc = 0; kc < 16; ++kc) {
            const float* wp = Wf1 + (size_t)(kc * 16 + 4 * g) * HI + w * 16 + c;
            f16x4 bf;
            bf[0] = (f16)wp[0]; bf[1] = (f16)wp[HI]; bf[2] = (f16)wp[2 * HI]; bf[3] = (f16)wp[3 * HI];
            #pragma unroll
            for (int m = 0; m < 4; ++m) {
                f16x4 af = *(const f16x4*)&aggL[m * 16 + c][kc * 16 + 4 * g];
                acc[m] = __builtin_amdgcn_mfma_f32_16x16x16f16(af, bf, acc[m], 0, 0, 0);
            }
        }
        float b = bf1[w * 16 + c];
        #pragma unroll
        for (int m = 0; m < 4; ++m)
            #pragma unroll
            for (int r = 0; r < 4; ++r)
                midL[m * 16 + 4 * g + r][w * 16 + c] = (f16)lrelu(acc[m][r] + b);
    }
    __syncthreads();

    #pragma unroll
    for (int nb = 0; nb < 2; ++nb) {
        int nt = w + nb * 4;
        f32x4 acc[4] = { z4, z4, z4, z4 };
        for (int kc = 0; kc < 4; ++kc) {
            const float* wp = Wf2 + (size_t)(kc * 16 + 4 * g) * OUT_DIM + nt * 16 + c;
            f16x4 bf;
            bf[0] = (f16)wp[0]; bf[1] = (f16)wp[OUT_DIM]; bf[2] = (f16)wp[2 * OUT_DIM]; bf[3] = (f16)wp[3 * OUT_DIM];
            #pragma unroll
            for (int m = 0; m < 4; ++m) {
                f16x4 af = *(const f16x4*)&midL[m * 16 + c][kc * 16 + 4 * g];
                acc[m] = __builtin_amdgcn_mfma_f32_16x16x16f16(af, bf, acc[m], 0, 0, 0);
            }
        }
        float b = bf2[nt * 16 + c];
        #pragma unroll
        for (int m = 0; m < 4; ++m)
            #pragma unroll
            for (int r = 0; r < 4; ++r) {
                int node = base + m * 16 + 4 * g + r;
                if (node < NN) out[(size_t)node * OUT_DIM + nt * 16 + c] = acc[m][r] + b;
            }
    }
}

extern "C" void kernel_launch(void* const* d_in, const int* in_sizes, int n_in,
                              void* d_out, int out_size, void* d_ws, size_t ws_size,
                              hipStream_t stream) {
    const float* x   = (const float*)d_in[0];
    const int*   ei  = (const int*)d_in[1];
    const float* Wi1 = (const float*)d_in[2];
    const float* bi1 = (const float*)d_in[3];
    const float* Wi2 = (const float*)d_in[4];
    const float* bi2 = (const float*)d_in[5];
    const float* Wa1 = (const float*)d_in[6];
    const float* ba1 = (const float*)d_in[7];
    const float* Wa2 = (const float*)d_in[8];
    const float* ba2 = (const float*)d_in[9];
    const float* Wf1 = (const float*)d_in[10];
    const float* bf1 = (const float*)d_in[11];
    const float* Wf2 = (const float*)d_in[12];
    const float* bf2 = (const float*)d_in[13];
    float* out = (float*)d_out;

    // layout (bytes):
    //   hs    [0,           51.2e6)  half NN*HF  (normalized in place by pass A)
    //   ssrc  [51.2e6,     102.4e6)  half        -> agg (half 51.2e6) after pass A
    //   sdst  [102.4e6,    153.6e6)  half        -> ed2 (int2 12.8e6) after pass A
    //   eatt  [153.6e6,    166.4e6)  half NE*H
    //   es2   [166.4e6,    179.2e6)  int2 NE
    //   cur_s [179.2e6,    179.6e6)  int NN
    //   cur_d [179.6e6,    180.0e6)  int NN
    //   bsum  [180.0e6,    +1564)    int NB_SCAN
    const size_t HS_B     = (size_t)NN * HF * sizeof(f16);           // 51.2e6
    const size_t OFF_SSRC = HS_B;
    const size_t OFF_SDST = 2 * HS_B;
    const size_t OFF_EATT = 3 * HS_B;
    const size_t OFF_ES2  = OFF_EATT + (size_t)NE * HEADS * sizeof(f16);
    const size_t OFF_CURS = OFF_ES2 + (size_t)NE * sizeof(int2);
    const size_t OFF_CURD = OFF_CURS + (size_t)NN * sizeof(int);
    const size_t OFF_BSUM = OFF_CURD + (size_t)NN * sizeof(int);
    const size_t NEED     = OFF_BSUM + NB_SCAN * sizeof(int);        // ~180.0 MB (<180.8 proven)
    if (ws_size < NEED) return;

    char* ws = (char*)d_ws;
    f16*  hs   = (f16*)(ws);
    f16*  ssrc = (f16*)(ws + OFF_SSRC);
    f16*  sdst = (f16*)(ws + OFF_SDST);
    f16*  eatt = (f16*)(ws + OFF_EATT);
    int2* es2  = (int2*)(ws + OFF_ES2);
    int*  cur_s = (int*)(ws + OFF_CURS);
    int*  cur_d = (int*)(ws + OFF_CURD);
    int*  bsum  = (int*)(ws + OFF_BSUM);
    f16*  agg  = (f16*)(ws + OFF_SSRC);       // aliases ssrc (dead after pass A)
    int2* ed2  = (int2*)(ws + OFF_SDST);      // aliases sdst (dead after pass A)

    const int NB64 = (NN + 63) / 64;

    k_embed<<<NB64, 256, 0, stream>>>(x, Wi1, bi1, Wi2, bi2, Wa1, hs, ssrc, sdst);

    // degrees for both CSRs, scans
    (void)hipMemsetAsync(cur_s, 0, 2 * (size_t)NN * sizeof(int), stream);  // cur_s+cur_d contiguous
    k_deg2<<<NE / 256, 256, 0, stream>>>(ei, cur_s, cur_d);
    k_scan1<<<NB_SCAN, 256, 0, stream>>>(cur_s, bsum);
    k_scan2<<<1, 256, 0, stream>>>(bsum);
    k_scan3<<<NB_SCAN, 256, 0, stream>>>(cur_s, bsum);
    k_scan1<<<NB_SCAN, 256, 0, stream>>>(cur_d, bsum);
    k_scan2<<<1, 256, 0, stream>>>(bsum);
    k_scan3<<<NB_SCAN, 256, 0, stream>>>(cur_d, bsum);

    // src fill + pass A
    k_fill_src<<<NE / 256, 256, 0, stream>>>(ei, cur_s, es2);
    k_edge_att_csr<<<NN / 4, 256, 0, stream>>>(es2, cur_s, ssrc, sdst, ba1, Wa2, ba2, eatt, hs);

    // dst fill (into dead sdst region) + pass B
    k_fill_dst<<<NE / 256, 256, 0, stream>>>(ei, cur_d, ed2);
    k_aggregate_csr<<<NN / 4, 256, 0, stream>>>(ed2, cur_d, hs, eatt, agg);

    k_out_mlp2<<<NB64, 256, 0, stream>>>(agg, Wf1, bf1, Wf2, bf2, out);
}

// Round 8
// 854.608 us; speedup vs baseline: 7.2333x; 1.0158x over previous
//
#include <hip/hip_runtime.h>
#include <hip/hip_fp16.h>

#define NN 100000
#define NE 1600000
#define HEADS 4
#define EM 64
#define HF 256      // HEADS*EM
#define IN_DIM 128
#define HI 64
#define OUT_DIM 128
#define NB_SCAN 391  // ceil(NN/256)

using f16 = _Float16;
typedef _Float16 f16x2 __attribute__((ext_vector_type(2)));
typedef _Float16 f16x4 __attribute__((ext_vector_type(4)));
typedef float f32x4 __attribute__((ext_vector_type(4)));

__device__ __forceinline__ float lrelu(float x) { return fmaxf(x, 0.01f * x); }

// =====================================================================
// k_embed: fused node MLP + attention projections, MFMA 16x16x16 f16.
// (unchanged — verified round 4)
// =====================================================================
__global__ __launch_bounds__(256) void k_embed(
    const float* __restrict__ x,
    const float* __restrict__ Wi1, const float* __restrict__ bi1,
    const float* __restrict__ Wi2, const float* __restrict__ bi2,
    const float* __restrict__ Wa1,
    f16* __restrict__ hs, f16* __restrict__ ssrc, f16* __restrict__ sdst)
{
    __shared__ __align__(16) char smem[73728];
    f16 (*xh)[136]      = (f16(*)[136])smem;
    f16 (*hsL)[64][72]  = (f16(*)[64][72])smem;
    f16 (*h1L)[64][72]  = (f16(*)[64][72])(smem + 36864);

    const int t = threadIdx.x;
    const int base = blockIdx.x * 64;

    #pragma unroll
    for (int i = 0; i < 8; ++i) {
        int q = t + i * 256;
        int row = q >> 5;
        int c4 = (q & 31) << 2;
        int gr = base + row; if (gr >= NN) gr = NN - 1;
        float4 v = *(const float4*)(x + (size_t)gr * IN_DIM + c4);
        f16x4 hv = { (f16)v.x, (f16)v.y, (f16)v.z, (f16)v.w };
        *(f16x4*)&xh[row][c4] = hv;
    }
    __syncthreads();

    const int h = t >> 6;
    const int l = t & 63;
    const int g = l >> 4;
    const int c = l & 15;

    const f32x4 z4 = { 0.f, 0.f, 0.f, 0.f };

    f32x4 acc1[4][4];
    #pragma unroll
    for (int m = 0; m < 4; ++m)
        #pragma unroll
        for (int n = 0; n < 4; ++n) acc1[m][n] = z4;

    {
        const float* W = Wi1 + (size_t)h * IN_DIM * EM;
        for (int kc = 0; kc < 8; ++kc) {
            f16x4 bf[4];
            #pragma unroll
            for (int n = 0; n < 4; ++n) {
                const float* wp = W + (size_t)(kc * 16 + 4 * g) * EM + n * 16 + c;
                f16x4 b;
                b[0] = (f16)wp[0]; b[1] = (f16)wp[EM]; b[2] = (f16)wp[2 * EM]; b[3] = (f16)wp[3 * EM];
                bf[n] = b;
            }
            #pragma unroll
            for (int m = 0; m < 4; ++m) {
                f16x4 af = *(const f16x4*)&xh[m * 16 + c][kc * 16 + 4 * g];
                #pragma unroll
                for (int n = 0; n < 4; ++n)
                    acc1[m][n] = __builtin_amdgcn_mfma_f32_16x16x16f16(af, bf[n], acc1[m][n], 0, 0, 0);
            }
        }
    }
    __syncthreads();

    #pragma unroll
    for (int n = 0; n < 4; ++n) {
        float b = bi1[h * EM + n * 16 + c];
        #pragma unroll
        for (int m = 0; m < 4; ++m)
            #pragma unroll
            for (int r = 0; r < 4; ++r)
                h1L[h][m * 16 + 4 * g + r][n * 16 + c] = (f16)lrelu(acc1[m][n][r] + b);
    }
    __syncthreads();

    f32x4 acc2[4][4];
    #pragma unroll
    for (int m = 0; m < 4; ++m)
        #pragma unroll
        for (int n = 0; n < 4; ++n) acc2[m][n] = z4;
    {
        const float* W = Wi2 + (size_t)h * EM * EM;
        for (int kc = 0; kc < 4; ++kc) {
            f16x4 bf[4];
            #pragma unroll
            for (int n = 0; n < 4; ++n) {
                const float* wp = W + (size_t)(kc * 16 + 4 * g) * EM + n * 16 + c;
                f16x4 b;
                b[0] = (f16)wp[0]; b[1] = (f16)wp[EM]; b[2] = (f16)wp[2 * EM]; b[3] = (f16)wp[3 * EM];
                bf[n] = b;
            }
            #pragma unroll
            for (int m = 0; m < 4; ++m) {
                f16x4 af = *(const f16x4*)&h1L[h][m * 16 + c][kc * 16 + 4 * g];
                #pragma unroll
                for (int n = 0; n < 4; ++n)
                    acc2[m][n] = __builtin_amdgcn_mfma_f32_16x16x16f16(af, bf[n], acc2[m][n], 0, 0, 0);
            }
        }
    }
    #pragma unroll
    for (int n = 0; n < 4; ++n) {
        float b = bi2[h * EM + n * 16 + c];
        #pragma unroll
        for (int m = 0; m < 4; ++m)
            #pragma unroll
            for (int r = 0; r < 4; ++r)
                hsL[h][m * 16 + 4 * g + r][n * 16 + c] = (f16)(acc2[m][n][r] + b);
    }
    __syncthreads();

    f16x4 af3[4][4];
    #pragma unroll
    for (int m = 0; m < 4; ++m)
        #pragma unroll
        for (int kc = 0; kc < 4; ++kc)
            af3[m][kc] = *(const f16x4*)&hsL[h][m * 16 + c][kc * 16 + 4 * g];

    const float* Wa = Wa1 + (size_t)h * (2 * EM) * HI;
    {
        f32x4 acc3[4][4];
        #pragma unroll
        for (int m = 0; m < 4; ++m)
            #pragma unroll
            for (int n = 0; n < 4; ++n) acc3[m][n] = z4;
        for (int kc = 0; kc < 4; ++kc) {
            f16x4 bf[4];
            #pragma unroll
            for (int n = 0; n < 4; ++n) {
                const float* wp = Wa + (size_t)(kc * 16 + 4 * g) * HI + n * 16 + c;
                f16x4 b;
                b[0] = (f16)wp[0]; b[1] = (f16)wp[HI]; b[2] = (f16)wp[2 * HI]; b[3] = (f16)wp[3 * HI];
                bf[n] = b;
            }
            #pragma unroll
            for (int m = 0; m < 4; ++m)
                #pragma unroll
                for (int n = 0; n < 4; ++n)
                    acc3[m][n] = __builtin_amdgcn_mfma_f32_16x16x16f16(af3[m][kc], bf[n], acc3[m][n], 0, 0, 0);
        }
        #pragma unroll
        for (int n = 0; n < 4; ++n)
            #pragma unroll
            for (int m = 0; m < 4; ++m)
                #pragma unroll
                for (int r = 0; r < 4; ++r)
                    h1L[h][m * 16 + 4 * g + r][n * 16 + c] = (f16)acc3[m][n][r];
    }
    f32x4 acc3b[4][4];
    #pragma unroll
    for (int m = 0; m < 4; ++m)
        #pragma unroll
        for (int n = 0; n < 4; ++n) acc3b[m][n] = z4;
    for (int kc = 0; kc < 4; ++kc) {
        f16x4 bf[4];
        #pragma unroll
        for (int n = 0; n < 4; ++n) {
            const float* wp = Wa + (size_t)(EM + kc * 16 + 4 * g) * HI + n * 16 + c;
            f16x4 b;
            b[0] = (f16)wp[0]; b[1] = (f16)wp[HI]; b[2] = (f16)wp[2 * HI]; b[3] = (f16)wp[3 * HI];
            bf[n] = b;
        }
        #pragma unroll
        for (int m = 0; m < 4; ++m)
            #pragma unroll
            for (int n = 0; n < 4; ++n)
                acc3b[m][n] = __builtin_amdgcn_mfma_f32_16x16x16f16(af3[m][kc], bf[n], acc3b[m][n], 0, 0, 0);
    }
    __syncthreads();

    #pragma unroll
    for (int i = 0; i < 8; ++i) {
        int q = t + i * 256;
        int hd = q >> 9, row = (q >> 3) & 63, c8 = (q & 7) << 3;
        int node = base + row;
        if (node < NN) {
            *(int4*)&hs[(size_t)node * HF + hd * EM + c8]   = *(int4*)&hsL[hd][row][c8];
            *(int4*)&ssrc[(size_t)node * HF + hd * EM + c8] = *(int4*)&h1L[hd][row][c8];
        }
    }
    __syncthreads();

    #pragma unroll
    for (int n = 0; n < 4; ++n)
        #pragma unroll
        for (int m = 0; m < 4; ++m)
            #pragma unroll
            for (int r = 0; r < 4; ++r)
                hsL[h][m * 16 + 4 * g + r][n * 16 + c] = (f16)acc3b[m][n][r];
    __syncthreads();
    #pragma unroll
    for (int i = 0; i < 8; ++i) {
        int q = t + i * 256;
        int hd = q >> 9, row = (q >> 3) & 63, c8 = (q & 7) << 3;
        int node = base + row;
        if (node < NN)
            *(int4*)&sdst[(size_t)node * HF + hd * EM + c8] = *(int4*)&hsL[hd][row][c8];
    }
}

// ---------------- CSR build ----------------
__global__ __launch_bounds__(256) void k_deg2(const int* __restrict__ ei,
                                              int* __restrict__ cs, int* __restrict__ cd)
{
    int e = blockIdx.x * 256 + threadIdx.x;
    atomicAdd(cs + ei[e], 1);
    atomicAdd(cd + ei[NE + e], 1);
}

// fused over both arrays: blocks [0,NB_SCAN) -> arr0, [NB_SCAN,2*NB_SCAN) -> arr0+NN
__global__ __launch_bounds__(256) void k_scan1(const int* __restrict__ arr0, int* __restrict__ bsum)
{
    const int t = threadIdx.x, lane = t & 63, w = t >> 6;
    const int half = (blockIdx.x >= NB_SCAN) ? 1 : 0;
    const int bb = blockIdx.x - half * NB_SCAN;
    const int* arr = arr0 + half * NN;
    int i = bb * 256 + t;
    int v = (i < NN) ? arr[i] : 0;
    #pragma unroll
    for (int d = 1; d < 64; d <<= 1) v += __shfl_xor(v, d);
    __shared__ int ws[4];
    if (lane == 0) ws[w] = v;
    __syncthreads();
    if (t == 0) bsum[blockIdx.x] = ws[0] + ws[1] + ws[2] + ws[3];
}

// 2 blocks: each scans its own NB_SCAN-run of bsum (exclusive, in place)
__global__ __launch_bounds__(256) void k_scan2(int* __restrict__ bsum0)
{
    __shared__ int wsum[4], woff[4];
    __shared__ int base, ctot;
    int* bsum = bsum0 + blockIdx.x * NB_SCAN;
    const int t = threadIdx.x, lane = t & 63, w = t >> 6;
    if (t == 0) base = 0;
    __syncthreads();
    for (int start = 0; start < NB_SCAN; start += 256) {
        int i = start + t;
        int v = (i < NB_SCAN) ? bsum[i] : 0;
        int incl = v;
        #pragma unroll
        for (int d = 1; d < 64; d <<= 1) {
            int u = __shfl_up(incl, d);
            if (lane >= d) incl += u;
        }
        if (lane == 63) wsum[w] = incl;
        __syncthreads();
        if (t == 0) {
            int s = 0;
            #pragma unroll
            for (int j = 0; j < 4; ++j) { int xv = wsum[j]; woff[j] = s; s += xv; }
            ctot = s;
        }
        __syncthreads();
        if (i < NB_SCAN) bsum[i] = base + woff[w] + incl - v;
        __syncthreads();
        if (t == 0) base += ctot;
        __syncthreads();
    }
}

__global__ __launch_bounds__(256) void k_scan3(int* __restrict__ arr0, const int* __restrict__ bsum)
{
    const int t = threadIdx.x, lane = t & 63, w = t >> 6;
    const int half = (blockIdx.x >= NB_SCAN) ? 1 : 0;
    const int bb = blockIdx.x - half * NB_SCAN;
    int* arr = arr0 + half * NN;
    int i = bb * 256 + t;
    int v = (i < NN) ? arr[i] : 0;
    int incl = v;
    #pragma unroll
    for (int d = 1; d < 64; d <<= 1) {
        int u = __shfl_up(incl, d);
        if (lane >= d) incl += u;
    }
    __shared__ int wsum[4], woff[4];
    if (lane == 63) wsum[w] = incl;
    __syncthreads();
    if (t == 0) {
        int s = 0;
        #pragma unroll
        for (int j = 0; j < 4; ++j) { int xv = wsum[j]; woff[j] = s; s += xv; }
    }
    __syncthreads();
    if (i < NN) arr[i] = bsum[blockIdx.x] + woff[w] + incl - v;
}

// fill src list: es2[pos] = {dst, e}
__global__ __launch_bounds__(256) void k_fill_src(const int* __restrict__ ei,
                                                  int* __restrict__ cur, int2* __restrict__ es2)
{
    int e = blockIdx.x * 256 + threadIdx.x;
    int src = ei[e], dst = ei[NE + e];
    int pos = atomicAdd(cur + src, 1);
    es2[pos] = make_int2(dst, e);
}

// fill dst list: ed2[pos] = {src, e}
__global__ __launch_bounds__(256) void k_fill_dst(const int* __restrict__ ei,
                                                  int* __restrict__ cur, int2* __restrict__ ed2)
{
    int e = blockIdx.x * 256 + threadIdx.x;
    int src = ei[e], dst = ei[NE + e];
    int pos = atomicAdd(cur + dst, 1);
    ed2[pos] = make_int2(src, e);
}

// ---------------- Pass A: src-CSR attention, packed f16, depth-4 pipeline ----------------
__global__ __launch_bounds__(256) void k_edge_att_csr(
    const int2* __restrict__ es2, const int* __restrict__ cur_s,
    const f16* __restrict__ ssrc, const f16* __restrict__ sdst,
    const float* __restrict__ ba1, const float* __restrict__ Wa2, const float* __restrict__ ba2,
    f16* __restrict__ eatt, f16* __restrict__ hs)
{
    const int wave = threadIdx.x >> 6;
    const int lane = threadIdx.x & 63;
    const int n = blockIdx.x * 4 + wave;
    const int h = lane >> 4;
    const int kq = lane & 15;

    const int beg = (n == 0) ? 0 : cur_s[n - 1];
    const int end = cur_s[n];
    if (beg >= end) return;

    const float4 ba1v = *(const float4*)(ba1 + h * EM + kq * 4);
    const float4 w2v  = *(const float4*)(Wa2 + h * EM + kq * 4);
    const float  ba2v = ba2[h];
    const f16x2 w01 = { (f16)w2v.x, (f16)w2v.y };
    const f16x2 w23 = { (f16)w2v.z, (f16)w2v.w };
    const f16x2 c001 = { (f16)0.01f, (f16)0.01f };

    const uint2* sd8 = (const uint2*)sdst;   // 8B units; row n -> n*64 + lane

    uint2 sv = ((const uint2*)(ssrc + (size_t)n * HF))[lane];
    const f16x2 z01 = *(f16x2*)&sv.x + (f16x2){ (f16)ba1v.x, (f16)ba1v.y };
    const f16x2 z23 = *(f16x2*)&sv.y + (f16x2){ (f16)ba1v.z, (f16)ba1v.w };

    float esum = 0.f;

#define COMP_A(eV, dV)                                                          \
    {                                                                           \
        f16x2 u01 = z01 + *(f16x2*)&dV.x;                                       \
        f16x2 u23 = z23 + *(f16x2*)&dV.y;                                       \
        u01 = __builtin_elementwise_max(u01, u01 * c001);                       \
        u23 = __builtin_elementwise_max(u23, u23 * c001);                       \
        f16x2 pr = u01 * w01 + u23 * w23;                                       \
        float pv = (float)pr.x + (float)pr.y;                                   \
        pv += __shfl_xor(pv, 1);                                                \
        pv += __shfl_xor(pv, 2);                                                \
        pv += __shfl_xor(pv, 4);                                                \
        pv += __shfl_xor(pv, 8);                                                \
        float a = pv + ba2v; a = fmaxf(a, 0.01f * a);                           \
        float eh = __expf(a);                                                   \
        esum += eh;                                                             \
        if (kq == 0) eatt[(size_t)eV.y * 4 + h] = (f16)eh;                      \
    }

    int p = beg;
    int2 e0, e1, e2, e3;
    uint2 d0, d1, d2, d3;
    e0 = es2[p]; d0 = sd8[(size_t)e0.x * 64 + lane];
    e1 = e0; d1 = d0; e2 = e0; d2 = d0; e3 = e0; d3 = d0;
    if (p + 1 < end) { e1 = es2[p + 1]; d1 = sd8[(size_t)e1.x * 64 + lane]; }
    if (p + 2 < end) { e2 = es2[p + 2]; d2 = sd8[(size_t)e2.x * 64 + lane]; }
    if (p + 3 < end) { e3 = es2[p + 3]; d3 = sd8[(size_t)e3.x * 64 + lane]; }

    while (p < end) {
        int2 f0 = e0, f1 = e1, f2 = e2, f3 = e3;
        uint2 g0 = d0, g1 = d1, g2 = d2, g3 = d3;
        if (p + 4 < end) { f0 = es2[p + 4]; g0 = sd8[(size_t)f0.x * 64 + lane]; }
        if (p + 5 < end) { f1 = es2[p + 5]; g1 = sd8[(size_t)f1.x * 64 + lane]; }
        if (p + 6 < end) { f2 = es2[p + 6]; g2 = sd8[(size_t)f2.x * 64 + lane]; }
        if (p + 7 < end) { f3 = es2[p + 7]; g3 = sd8[(size_t)f3.x * 64 + lane]; }
        const int rem = end - p;
        COMP_A(e0, d0);
        if (rem > 1) COMP_A(e1, d1);
        if (rem > 2) COMP_A(e2, d2);
        if (rem > 3) COMP_A(e3, d3);
        e0 = f0; d0 = g0; e1 = f1; d1 = g1; e2 = f2; d2 = g2; e3 = f3; d3 = g3;
        p += 4;
    }
#undef COMP_A

    // fold 1/esum into hs (row owned by this wave)
    float inv = 1.f / esum;
    uint2* hrow = (uint2*)(hs + (size_t)n * HF);
    uint2 hv = hrow[lane];
    f16x2 h0 = *(f16x2*)&hv.x, h1 = *(f16x2*)&hv.y;
    uint2 o;
    f16x2 r0 = { (f16)((float)h0.x * inv), (f16)((float)h0.y * inv) };
    f16x2 r1 = { (f16)((float)h1.x * inv), (f16)((float)h1.y * inv) };
    *(f16x2*)&o.x = r0;
    *(f16x2*)&o.y = r1;
    hrow[lane] = o;
}

// ---------------- Pass B: dst-CSR gather aggregation, depth-4 pipeline ----------------
__global__ __launch_bounds__(256) void k_aggregate_csr(
    const int2* __restrict__ ed2, const int* __restrict__ cur_d,
    const f16* __restrict__ hs, const f16* __restrict__ eatt,
    f16* __restrict__ agg)
{
    const int wave = threadIdx.x >> 6;
    const int lane = threadIdx.x & 63;
    const int n = blockIdx.x * 4 + wave;
    const int h = lane >> 4;

    const int beg = (n == 0) ? 0 : cur_d[n - 1];
    const int end = cur_d[n];

    const uint2* hs8 = (const uint2*)hs;     // 8B units
    const uint2* at8 = (const uint2*)eatt;   // eatt[e] = 4 halves = 8B

    float a0 = 0.f, a1 = 0.f, a2 = 0.f, a3 = 0.f;

#define COMP_B(atV, hV)                                                         \
    {                                                                           \
        uint sel = (h & 2) ? atV.y : atV.x;                                     \
        f16x2 selh = *(f16x2*)&sel;                                             \
        float al = (float)((h & 1) ? selh.y : selh.x);                          \
        f16x2 f01 = *(f16x2*)&hV.x;                                             \
        f16x2 f23 = *(f16x2*)&hV.y;                                             \
        a0 = fmaf((float)f01.x, al, a0); a1 = fmaf((float)f01.y, al, a1);       \
        a2 = fmaf((float)f23.x, al, a2); a3 = fmaf((float)f23.y, al, a3);       \
    }

    if (beg < end) {
        int p = beg;
        uint2 t0, t1, t2, t3;
        uint2 v0, v1, v2, v3;
        {
            int2 s = ed2[p];
            t0 = at8[s.y]; v0 = hs8[(size_t)s.x * 64 + lane];
        }
        t1 = t0; v1 = v0; t2 = t0; v2 = v0; t3 = t0; v3 = v0;
        if (p + 1 < end) { int2 s = ed2[p + 1]; t1 = at8[s.y]; v1 = hs8[(size_t)s.x * 64 + lane]; }
        if (p + 2 < end) { int2 s = ed2[p + 2]; t2 = at8[s.y]; v2 = hs8[(size_t)s.x * 64 + lane]; }
        if (p + 3 < end) { int2 s = ed2[p + 3]; t3 = at8[s.y]; v3 = hs8[(size_t)s.x * 64 + lane]; }

        while (p < end) {
            uint2 u0 = t0, u1 = t1, u2 = t2, u3 = t3;
            uint2 w0 = v0, w1 = v1, w2 = v2, w3 = v3;
            if (p + 4 < end) { int2 s = ed2[p + 4]; u0 = at8[s.y]; w0 = hs8[(size_t)s.x * 64 + lane]; }
            if (p + 5 < end) { int2 s = ed2[p + 5]; u1 = at8[s.y]; w1 = hs8[(size_t)s.x * 64 + lane]; }
            if (p + 6 < end) { int2 s = ed2[p + 6]; u2 = at8[s.y]; w2 = hs8[(size_t)s.x * 64 + lane]; }
            if (p + 7 < end) { int2 s = ed2[p + 7]; u3 = at8[s.y]; w3 = hs8[(size_t)s.x * 64 + lane]; }
            const int rem = end - p;
            COMP_B(t0, v0);
            if (rem > 1) COMP_B(t1, v1);
            if (rem > 2) COMP_B(t2, v2);
            if (rem > 3) COMP_B(t3, v3);
            t0 = u0; v0 = w0; t1 = u1; v1 = w1; t2 = u2; v2 = w2; t3 = u3; v3 = w3;
            p += 4;
        }
    }
#undef COMP_B

    uint2 o;
    f16x2 r0 = { (f16)a0, (f16)a1 };
    f16x2 r1 = { (f16)a2, (f16)a3 };
    *(f16x2*)&o.x = r0;
    *(f16x2*)&o.y = r1;
    ((uint2*)(agg + (size_t)n * HF))[lane] = o;
}

// =====================================================================
// k_out_mlp2 (unchanged — verified round 4)
// =====================================================================
__global__ __launch_bounds__(256) void k_out_mlp2(
    const f16* __restrict__ agg,
    const float* __restrict__ Wf1, const float* __restrict__ bf1,
    const float* __restrict__ Wf2, const float* __restrict__ bf2,
    float* __restrict__ out)
{
    __shared__ __align__(16) f16 aggL[64][272];
    __shared__ __align__(16) f16 midL[64][72];

    const int t = threadIdx.x;
    const int base = blockIdx.x * 64;

    #pragma unroll
    for (int i = 0; i < 8; ++i) {
        int q = t + i * 256;
        int row = q >> 5, c8 = (q & 31) << 3;
        int gr = base + row; if (gr >= NN) gr = NN - 1;
        *(int4*)&aggL[row][c8] = *(const int4*)&agg[(size_t)gr * HF + c8];
    }
    __syncthreads();

    const int w = t >> 6, l = t & 63;
    const int g = l >> 4, c = l & 15;
    const f32x4 z4 = { 0.f, 0.f, 0.f, 0.f };

    {
        f32x4 acc[4] = { z4, z4, z4, z4 };
        for (int kc = 0; kc < 16; ++kc) {
            const float* wp = Wf1 + (size_t)(kc * 16 + 4 * g) * HI + w * 16 + c;
            f16x4 bf;
            bf[0] = (f16)wp[0]; bf[1] = (f16)wp[HI]; bf[2] = (f16)wp[2 * HI]; bf[3] = (f16)wp[3 * HI];
            #pragma unroll
            for (int m = 0; m < 4; ++m) {
                f16x4 af = *(const f16x4*)&aggL[m * 16 + c][kc * 16 + 4 * g];
                acc[m] = __builtin_amdgcn_mfma_f32_16x16x16f16(af, bf, acc[m], 0, 0, 0);
            }
        }
        float b = bf1[w * 16 + c];
        #pragma unroll
        for (int m = 0; m < 4; ++m)
            #pragma unroll
            for (int r = 0; r < 4; ++r)
                midL[m * 16 + 4 * g + r][w * 16 + c] = (f16)lrelu(acc[m][r] + b);
    }
    __syncthreads();

    #pragma unroll
    for (int nb = 0; nb < 2; ++nb) {
        int nt = w + nb * 4;
        f32x4 acc[4] = { z4, z4, z4, z4 };
        for (int kc = 0; kc < 4; ++kc) {
            const float* wp = Wf2 + (size_t)(kc * 16 + 4 * g) * OUT_DIM + nt * 16 + c;
            f16x4 bf;
            bf[0] = (f16)wp[0]; bf[1] = (f16)wp[OUT_DIM]; bf[2] = (f16)wp[2 * OUT_DIM]; bf[3] = (f16)wp[3 * OUT_DIM];
            #pragma unroll
            for (int m = 0; m < 4; ++m) {
                f16x4 af = *(const f16x4*)&midL[m * 16 + c][kc * 16 + 4 * g];
                acc[m] = __builtin_amdgcn_mfma_f32_16x16x16f16(af, bf, acc[m], 0, 0, 0);
            }
        }
        float b = bf2[nt * 16 + c];
        #pragma unroll
        for (int m = 0; m < 4; ++m)
            #pragma unroll
            for (int r = 0; r < 4; ++r) {
                int node = base + m * 16 + 4 * g + r;
                if (node < NN) out[(size_t)node * OUT_DIM + nt * 16 + c] = acc[m][r] + b;
            }
    }
}

extern "C" void kernel_launch(void* const* d_in, const int* in_sizes, int n_in,
                              void* d_out, int out_size, void* d_ws, size_t ws_size,
                              hipStream_t stream) {
    const float* x   = (const float*)d_in[0];
    const int*   ei  = (const int*)d_in[1];
    const float* Wi1 = (const float*)d_in[2];
    const float* bi1 = (const float*)d_in[3];
    const float* Wi2 = (const float*)d_in[4];
    const float* bi2 = (const float*)d_in[5];
    const float* Wa1 = (const float*)d_in[6];
    const float* ba1 = (const float*)d_in[7];
    const float* Wa2 = (const float*)d_in[8];
    const float* ba2 = (const float*)d_in[9];
    const float* Wf1 = (const float*)d_in[10];
    const float* bf1 = (const float*)d_in[11];
    const float* Wf2 = (const float*)d_in[12];
    const float* bf2 = (const float*)d_in[13];
    float* out = (float*)d_out;

    const size_t HS_B     = (size_t)NN * HF * sizeof(f16);           // 51.2e6
    const size_t OFF_SSRC = HS_B;
    const size_t OFF_SDST = 2 * HS_B;
    const size_t OFF_EATT = 3 * HS_B;
    const size_t OFF_ES2  = OFF_EATT + (size_t)NE * HEADS * sizeof(f16);
    const size_t OFF_CURS = OFF_ES2 + (size_t)NE * sizeof(int2);
    const size_t OFF_CURD = OFF_CURS + (size_t)NN * sizeof(int);
    const size_t OFF_BSUM = OFF_CURD + (size_t)NN * sizeof(int);
    const size_t NEED     = OFF_BSUM + 2 * NB_SCAN * sizeof(int);    // ~180.0 MB (<180.8 proven)
    if (ws_size < NEED) return;

    char* ws = (char*)d_ws;
    f16*  hs   = (f16*)(ws);
    f16*  ssrc = (f16*)(ws + OFF_SSRC);
    f16*  sdst = (f16*)(ws + OFF_SDST);
    f16*  eatt = (f16*)(ws + OFF_EATT);
    int2* es2  = (int2*)(ws + OFF_ES2);
    int*  cur_s = (int*)(ws + OFF_CURS);
    int*  cur_d = (int*)(ws + OFF_CURD);
    int*  bsum  = (int*)(ws + OFF_BSUM);
    f16*  agg  = (f16*)(ws + OFF_SSRC);       // aliases ssrc (dead after pass A)
    int2* ed2  = (int2*)(ws + OFF_SDST);      // aliases sdst (dead after pass A)

    const int NB64 = (NN + 63) / 64;

    k_embed<<<NB64, 256, 0, stream>>>(x, Wi1, bi1, Wi2, bi2, Wa1, hs, ssrc, sdst);

    // degrees for both CSRs, fused scans
    (void)hipMemsetAsync(cur_s, 0, 2 * (size_t)NN * sizeof(int), stream);  // cur_s+cur_d contiguous
    k_deg2<<<NE / 256, 256, 0, stream>>>(ei, cur_s, cur_d);
    k_scan1<<<2 * NB_SCAN, 256, 0, stream>>>(cur_s, bsum);
    k_scan2<<<2, 256, 0, stream>>>(bsum);
    k_scan3<<<2 * NB_SCAN, 256, 0, stream>>>(cur_s, bsum);

    // src fill + pass A
    k_fill_src<<<NE / 256, 256, 0, stream>>>(ei, cur_s, es2);
    k_edge_att_csr<<<NN / 4, 256, 0, stream>>>(es2, cur_s, ssrc, sdst, ba1, Wa2, ba2, eatt, hs);

    // dst fill (into dead sdst region) + pass B
    k_fill_dst<<<NE / 256, 256, 0, stream>>>(ei, cur_d, ed2);
    k_aggregate_csr<<<NN / 4, 256, 0, stream>>>(ed2, cur_d, hs, eatt, agg);

    k_out_mlp2<<<NB64, 256, 0, stream>>>(agg, Wf1, bf1, Wf2, bf2, out);
}

// Round 9
// 781.014 us; speedup vs baseline: 7.9149x; 1.0942x over previous
//
#include <hip/hip_runtime.h>
#include <hip/hip_fp16.h>

#define NN 100000
#define NE 1600000
#define HEADS 4
#define EM 64
#define HF 256      // HEADS*EM
#define IN_DIM 128
#define HI 64
#define OUT_DIM 128
#define NB_SCAN 391  // ceil(NN/256)

using f16 = _Float16;
typedef _Float16 f16x2 __attribute__((ext_vector_type(2)));
typedef _Float16 f16x4 __attribute__((ext_vector_type(4)));
typedef float f32x4 __attribute__((ext_vector_type(4)));

__device__ __forceinline__ float lrelu(float x) { return fmaxf(x, 0.01f * x); }

// =====================================================================
// k_embed: fused node MLP + attention projections, MFMA 16x16x16 f16.
// (unchanged — verified round 4)
// =====================================================================
__global__ __launch_bounds__(256) void k_embed(
    const float* __restrict__ x,
    const float* __restrict__ Wi1, const float* __restrict__ bi1,
    const float* __restrict__ Wi2, const float* __restrict__ bi2,
    const float* __restrict__ Wa1,
    f16* __restrict__ hs, f16* __restrict__ ssrc, f16* __restrict__ sdst)
{
    __shared__ __align__(16) char smem[73728];
    f16 (*xh)[136]      = (f16(*)[136])smem;
    f16 (*hsL)[64][72]  = (f16(*)[64][72])smem;
    f16 (*h1L)[64][72]  = (f16(*)[64][72])(smem + 36864);

    const int t = threadIdx.x;
    const int base = blockIdx.x * 64;

    #pragma unroll
    for (int i = 0; i < 8; ++i) {
        int q = t + i * 256;
        int row = q >> 5;
        int c4 = (q & 31) << 2;
        int gr = base + row; if (gr >= NN) gr = NN - 1;
        float4 v = *(const float4*)(x + (size_t)gr * IN_DIM + c4);
        f16x4 hv = { (f16)v.x, (f16)v.y, (f16)v.z, (f16)v.w };
        *(f16x4*)&xh[row][c4] = hv;
    }
    __syncthreads();

    const int h = t >> 6;
    const int l = t & 63;
    const int g = l >> 4;
    const int c = l & 15;

    const f32x4 z4 = { 0.f, 0.f, 0.f, 0.f };

    f32x4 acc1[4][4];
    #pragma unroll
    for (int m = 0; m < 4; ++m)
        #pragma unroll
        for (int n = 0; n < 4; ++n) acc1[m][n] = z4;

    {
        const float* W = Wi1 + (size_t)h * IN_DIM * EM;
        for (int kc = 0; kc < 8; ++kc) {
            f16x4 bf[4];
            #pragma unroll
            for (int n = 0; n < 4; ++n) {
                const float* wp = W + (size_t)(kc * 16 + 4 * g) * EM + n * 16 + c;
                f16x4 b;
                b[0] = (f16)wp[0]; b[1] = (f16)wp[EM]; b[2] = (f16)wp[2 * EM]; b[3] = (f16)wp[3 * EM];
                bf[n] = b;
            }
            #pragma unroll
            for (int m = 0; m < 4; ++m) {
                f16x4 af = *(const f16x4*)&xh[m * 16 + c][kc * 16 + 4 * g];
                #pragma unroll
                for (int n = 0; n < 4; ++n)
                    acc1[m][n] = __builtin_amdgcn_mfma_f32_16x16x16f16(af, bf[n], acc1[m][n], 0, 0, 0);
            }
        }
    }
    __syncthreads();

    #pragma unroll
    for (int n = 0; n < 4; ++n) {
        float b = bi1[h * EM + n * 16 + c];
        #pragma unroll
        for (int m = 0; m < 4; ++m)
            #pragma unroll
            for (int r = 0; r < 4; ++r)
                h1L[h][m * 16 + 4 * g + r][n * 16 + c] = (f16)lrelu(acc1[m][n][r] + b);
    }
    __syncthreads();

    f32x4 acc2[4][4];
    #pragma unroll
    for (int m = 0; m < 4; ++m)
        #pragma unroll
        for (int n = 0; n < 4; ++n) acc2[m][n] = z4;
    {
        const float* W = Wi2 + (size_t)h * EM * EM;
        for (int kc = 0; kc < 4; ++kc) {
            f16x4 bf[4];
            #pragma unroll
            for (int n = 0; n < 4; ++n) {
                const float* wp = W + (size_t)(kc * 16 + 4 * g) * EM + n * 16 + c;
                f16x4 b;
                b[0] = (f16)wp[0]; b[1] = (f16)wp[EM]; b[2] = (f16)wp[2 * EM]; b[3] = (f16)wp[3 * EM];
                bf[n] = b;
            }
            #pragma unroll
            for (int m = 0; m < 4; ++m) {
                f16x4 af = *(const f16x4*)&h1L[h][m * 16 + c][kc * 16 + 4 * g];
                #pragma unroll
                for (int n = 0; n < 4; ++n)
                    acc2[m][n] = __builtin_amdgcn_mfma_f32_16x16x16f16(af, bf[n], acc2[m][n], 0, 0, 0);
            }
        }
    }
    #pragma unroll
    for (int n = 0; n < 4; ++n) {
        float b = bi2[h * EM + n * 16 + c];
        #pragma unroll
        for (int m = 0; m < 4; ++m)
            #pragma unroll
            for (int r = 0; r < 4; ++r)
                hsL[h][m * 16 + 4 * g + r][n * 16 + c] = (f16)(acc2[m][n][r] + b);
    }
    __syncthreads();

    f16x4 af3[4][4];
    #pragma unroll
    for (int m = 0; m < 4; ++m)
        #pragma unroll
        for (int kc = 0; kc < 4; ++kc)
            af3[m][kc] = *(const f16x4*)&hsL[h][m * 16 + c][kc * 16 + 4 * g];

    const float* Wa = Wa1 + (size_t)h * (2 * EM) * HI;
    {
        f32x4 acc3[4][4];
        #pragma unroll
        for (int m = 0; m < 4; ++m)
            #pragma unroll
            for (int n = 0; n < 4; ++n) acc3[m][n] = z4;
        for (int kc = 0; kc < 4; ++kc) {
            f16x4 bf[4];
            #pragma unroll
            for (int n = 0; n < 4; ++n) {
                const float* wp = Wa + (size_t)(kc * 16 + 4 * g) * HI + n * 16 + c;
                f16x4 b;
                b[0] = (f16)wp[0]; b[1] = (f16)wp[HI]; b[2] = (f16)wp[2 * HI]; b[3] = (f16)wp[3 * HI];
                bf[n] = b;
            }
            #pragma unroll
            for (int m = 0; m < 4; ++m)
                #pragma unroll
                for (int n = 0; n < 4; ++n)
                    acc3[m][n] = __builtin_amdgcn_mfma_f32_16x16x16f16(af3[m][kc], bf[n], acc3[m][n], 0, 0, 0);
        }
        #pragma unroll
        for (int n = 0; n < 4; ++n)
            #pragma unroll
            for (int m = 0; m < 4; ++m)
                #pragma unroll
                for (int r = 0; r < 4; ++r)
                    h1L[h][m * 16 + 4 * g + r][n * 16 + c] = (f16)acc3[m][n][r];
    }
    f32x4 acc3b[4][4];
    #pragma unroll
    for (int m = 0; m < 4; ++m)
        #pragma unroll
        for (int n = 0; n < 4; ++n) acc3b[m][n] = z4;
    for (int kc = 0; kc < 4; ++kc) {
        f16x4 bf[4];
        #pragma unroll
        for (int n = 0; n < 4; ++n) {
            const float* wp = Wa + (size_t)(EM + kc * 16 + 4 * g) * HI + n * 16 + c;
            f16x4 b;
            b[0] = (f16)wp[0]; b[1] = (f16)wp[HI]; b[2] = (f16)wp[2 * HI]; b[3] = (f16)wp[3 * HI];
            bf[n] = b;
        }
        #pragma unroll
        for (int m = 0; m < 4; ++m)
            #pragma unroll
            for (int n = 0; n < 4; ++n)
                acc3b[m][n] = __builtin_amdgcn_mfma_f32_16x16x16f16(af3[m][kc], bf[n], acc3b[m][n], 0, 0, 0);
    }
    __syncthreads();

    #pragma unroll
    for (int i = 0; i < 8; ++i) {
        int q = t + i * 256;
        int hd = q >> 9, row = (q >> 3) & 63, c8 = (q & 7) << 3;
        int node = base + row;
        if (node < NN) {
            *(int4*)&hs[(size_t)node * HF + hd * EM + c8]   = *(int4*)&hsL[hd][row][c8];
            *(int4*)&ssrc[(size_t)node * HF + hd * EM + c8] = *(int4*)&h1L[hd][row][c8];
        }
    }
    __syncthreads();

    #pragma unroll
    for (int n = 0; n < 4; ++n)
        #pragma unroll
        for (int m = 0; m < 4; ++m)
            #pragma unroll
            for (int r = 0; r < 4; ++r)
                hsL[h][m * 16 + 4 * g + r][n * 16 + c] = (f16)acc3b[m][n][r];
    __syncthreads();
    #pragma unroll
    for (int i = 0; i < 8; ++i) {
        int q = t + i * 256;
        int hd = q >> 9, row = (q >> 3) & 63, c8 = (q & 7) << 3;
        int node = base + row;
        if (node < NN)
            *(int4*)&sdst[(size_t)node * HF + hd * EM + c8] = *(int4*)&hsL[hd][row][c8];
    }
}

// ---------------- CSR build (unchanged) ----------------
__global__ __launch_bounds__(256) void k_deg2(const int* __restrict__ ei,
                                              int* __restrict__ cs, int* __restrict__ cd)
{
    int e = blockIdx.x * 256 + threadIdx.x;
    atomicAdd(cs + ei[e], 1);
    atomicAdd(cd + ei[NE + e], 1);
}

__global__ __launch_bounds__(256) void k_scan1(const int* __restrict__ arr0, int* __restrict__ bsum)
{
    const int t = threadIdx.x, lane = t & 63, w = t >> 6;
    const int half = (blockIdx.x >= NB_SCAN) ? 1 : 0;
    const int bb = blockIdx.x - half * NB_SCAN;
    const int* arr = arr0 + half * NN;
    int i = bb * 256 + t;
    int v = (i < NN) ? arr[i] : 0;
    #pragma unroll
    for (int d = 1; d < 64; d <<= 1) v += __shfl_xor(v, d);
    __shared__ int ws[4];
    if (lane == 0) ws[w] = v;
    __syncthreads();
    if (t == 0) bsum[blockIdx.x] = ws[0] + ws[1] + ws[2] + ws[3];
}

__global__ __launch_bounds__(256) void k_scan2(int* __restrict__ bsum0)
{
    __shared__ int wsum[4], woff[4];
    __shared__ int base, ctot;
    int* bsum = bsum0 + blockIdx.x * NB_SCAN;
    const int t = threadIdx.x, lane = t & 63, w = t >> 6;
    if (t == 0) base = 0;
    __syncthreads();
    for (int start = 0; start < NB_SCAN; start += 256) {
        int i = start + t;
        int v = (i < NB_SCAN) ? bsum[i] : 0;
        int incl = v;
        #pragma unroll
        for (int d = 1; d < 64; d <<= 1) {
            int u = __shfl_up(incl, d);
            if (lane >= d) incl += u;
        }
        if (lane == 63) wsum[w] = incl;
        __syncthreads();
        if (t == 0) {
            int s = 0;
            #pragma unroll
            for (int j = 0; j < 4; ++j) { int xv = wsum[j]; woff[j] = s; s += xv; }
            ctot = s;
        }
        __syncthreads();
        if (i < NB_SCAN) bsum[i] = base + woff[w] + incl - v;
        __syncthreads();
        if (t == 0) base += ctot;
        __syncthreads();
    }
}

__global__ __launch_bounds__(256) void k_scan3(int* __restrict__ arr0, const int* __restrict__ bsum)
{
    const int t = threadIdx.x, lane = t & 63, w = t >> 6;
    const int half = (blockIdx.x >= NB_SCAN) ? 1 : 0;
    const int bb = blockIdx.x - half * NB_SCAN;
    int* arr = arr0 + half * NN;
    int i = bb * 256 + t;
    int v = (i < NN) ? arr[i] : 0;
    int incl = v;
    #pragma unroll
    for (int d = 1; d < 64; d <<= 1) {
        int u = __shfl_up(incl, d);
        if (lane >= d) incl += u;
    }
    __shared__ int wsum[4], woff[4];
    if (lane == 63) wsum[w] = incl;
    __syncthreads();
    if (t == 0) {
        int s = 0;
        #pragma unroll
        for (int j = 0; j < 4; ++j) { int xv = wsum[j]; woff[j] = s; s += xv; }
    }
    __syncthreads();
    if (i < NN) arr[i] = bsum[blockIdx.x] + woff[w] + incl - v;
}

__global__ __launch_bounds__(256) void k_fill_src(const int* __restrict__ ei,
                                                  int* __restrict__ cur, int2* __restrict__ es2)
{
    int e = blockIdx.x * 256 + threadIdx.x;
    int src = ei[e], dst = ei[NE + e];
    int pos = atomicAdd(cur + src, 1);
    es2[pos] = make_int2(dst, e);
}

__global__ __launch_bounds__(256) void k_fill_dst(const int* __restrict__ ei,
                                                  int* __restrict__ cur, int2* __restrict__ ed2)
{
    int e = blockIdx.x * 256 + threadIdx.x;
    int src = ei[e], dst = ei[NE + e];
    int pos = atomicAdd(cur + dst, 1);
    ed2[pos] = make_int2(src, e);
}

// ---------------- Pass A: src-CSR attention, 4 edges/wave x 16 lanes/edge ----------------
// lane = 16*eidx + q; lane covers features 16q..16q+15 (one head: h = q>>2)
__global__ __launch_bounds__(256) void k_edge_att_csr(
    const int2* __restrict__ es2, const int* __restrict__ cur_s,
    const f16* __restrict__ ssrc, const f16* __restrict__ sdst,
    const float* __restrict__ ba1, const float* __restrict__ Wa2, const float* __restrict__ ba2,
    f16* __restrict__ eatt, f16* __restrict__ hs)
{
    const int wave = threadIdx.x >> 6;
    const int lane = threadIdx.x & 63;
    const int n = blockIdx.x * 4 + wave;
    const int eidx = lane >> 4;
    const int q = lane & 15;
    const int h = q >> 2;
    const int fb = q * 16;

    const int beg = (n == 0) ? 0 : cur_s[n - 1];
    const int end = cur_s[n];
    if (beg >= end) return;

    // per-lane constants: z = ssrc[n][fb..fb+15] + ba1[fb..], w2[fb..], as 8 f16x2
    f16x2 z[8], w[8];
    {
        const int4* sr = (const int4*)(ssrc + (size_t)n * HF + fb);
        int4 s0 = sr[0], s1 = sr[1];
        const f16x2* sp0 = (const f16x2*)&s0;
        const f16x2* sp1 = (const f16x2*)&s1;
        const float4* bb = (const float4*)(ba1 + fb);
        const float4* wwp = (const float4*)(Wa2 + fb);
        #pragma unroll
        for (int j = 0; j < 4; ++j) {
            float4 b4 = bb[j];
            float4 w4 = wwp[j];
            f16x2 blo = { (f16)b4.x, (f16)b4.y }, bhi = { (f16)b4.z, (f16)b4.w };
            f16x2 wlo = { (f16)w4.x, (f16)w4.y }, whi = { (f16)w4.z, (f16)w4.w };
            f16x2 sv = (j < 2) ? sp0[2 * j] : sp1[2 * (j - 2)];
            f16x2 sv2 = (j < 2) ? sp0[2 * j + 1] : sp1[2 * (j - 2) + 1];
            z[2 * j] = sv + blo;
            z[2 * j + 1] = sv2 + bhi;
            w[2 * j] = wlo;
            w[2 * j + 1] = whi;
        }
    }
    const float ba2v = ba2[h];
    const f16x2 c001 = { (f16)0.01f, (f16)0.01f };

    float esumv = 0.f;

    int p = beg;
    int idx0 = p + eidx; if (idx0 > end - 1) idx0 = end - 1;
    bool val = (p + eidx) < end;
    int2 rec = es2[idx0];
    const int4* dr = (const int4*)(sdst + (size_t)rec.x * HF + fb);
    int4 d0 = dr[0], d1 = dr[1];
    int e_cur = rec.y;

    while (p < end) {
        const int pn = p + 4;
        int4 nd0 = d0, nd1 = d1;
        int e_nxt = e_cur;
        bool val_n = false;
        if (pn < end) {
            int idx = pn + eidx; if (idx > end - 1) idx = end - 1;
            val_n = (pn + eidx) < end;
            int2 r2 = es2[idx];
            const int4* dr2 = (const int4*)(sdst + (size_t)r2.x * HF + fb);
            nd0 = dr2[0]; nd1 = dr2[1];
            e_nxt = r2.y;
        }

        // dot over this lane's 16 features
        const f16x2* dp0 = (const f16x2*)&d0;
        const f16x2* dp1 = (const f16x2*)&d1;
        f16x2 pr = { (f16)0.f, (f16)0.f };
        #pragma unroll
        for (int j = 0; j < 4; ++j) {
            f16x2 u = z[j] + dp0[j];
            u = __builtin_elementwise_max(u, u * c001);
            pr += u * w[j];
        }
        #pragma unroll
        for (int j = 0; j < 4; ++j) {
            f16x2 u = z[4 + j] + dp1[j];
            u = __builtin_elementwise_max(u, u * c001);
            pr += u * w[4 + j];
        }
        float s = (float)pr.x + (float)pr.y;
        s += __shfl_xor(s, 1);
        s += __shfl_xor(s, 2);
        float a = s + ba2v;
        a = fmaxf(a, 0.01f * a);
        float eh = val ? __expf(a) : 0.f;
        esumv += eh;
        if (val && (q & 3) == 0) eatt[(size_t)e_cur * 4 + h] = (f16)eh;

        d0 = nd0; d1 = nd1; e_cur = e_nxt; val = val_n;
        p = pn;
    }

    // cross-group esum (same head across eidx groups)
    esumv += __shfl_xor(esumv, 16);
    esumv += __shfl_xor(esumv, 32);

    // normalize hs row: 16 lanes (eidx==0), each scales its 16 features by 1/esum(head)
    if (eidx == 0) {
        float inv = 1.f / esumv;
        int4* hr = (int4*)(hs + (size_t)n * HF + fb);
        int4 h0 = hr[0], h1 = hr[1];
        f16x2* hp0 = (f16x2*)&h0;
        f16x2* hp1 = (f16x2*)&h1;
        #pragma unroll
        for (int j = 0; j < 4; ++j) {
            f16x2 v0 = hp0[j], v1 = hp1[j];
            hp0[j] = (f16x2){ (f16)((float)v0.x * inv), (f16)((float)v0.y * inv) };
            hp1[j] = (f16x2){ (f16)((float)v1.x * inv), (f16)((float)v1.y * inv) };
        }
        hr[0] = h0; hr[1] = h1;
    }
}

// ---------------- Pass B: dst-CSR aggregation, 4 edges/wave x 16 lanes/edge ----------------
__global__ __launch_bounds__(256) void k_aggregate_csr(
    const int2* __restrict__ ed2, const int* __restrict__ cur_d,
    const f16* __restrict__ hs, const f16* __restrict__ eatt,
    f16* __restrict__ agg)
{
    const int wave = threadIdx.x >> 6;
    const int lane = threadIdx.x & 63;
    const int n = blockIdx.x * 4 + wave;
    const int eidx = lane >> 4;
    const int q = lane & 15;
    const int h = q >> 2;
    const int fb = q * 16;

    const int beg = (n == 0) ? 0 : cur_d[n - 1];
    const int end = cur_d[n];

    const unsigned short* at = (const unsigned short*)eatt;

    float acc[16];
    #pragma unroll
    for (int j = 0; j < 16; ++j) acc[j] = 0.f;

    if (beg < end) {
        int p = beg;
        int idx0 = p + eidx; if (idx0 > end - 1) idx0 = end - 1;
        bool val = (p + eidx) < end;
        int2 rec = ed2[idx0];
        const int4* hr = (const int4*)(hs + (size_t)rec.x * HF + fb);
        int4 v0 = hr[0], v1 = hr[1];
        unsigned short av = at[(size_t)rec.y * 4 + h];

        while (p < end) {
            const int pn = p + 4;
            int4 nv0 = v0, nv1 = v1;
            unsigned short nav = av;
            bool val_n = false;
            if (pn < end) {
                int idx = pn + eidx; if (idx > end - 1) idx = end - 1;
                val_n = (pn + eidx) < end;
                int2 r2 = ed2[idx];
                const int4* hr2 = (const int4*)(hs + (size_t)r2.x * HF + fb);
                nv0 = hr2[0]; nv1 = hr2[1];
                nav = at[(size_t)r2.y * 4 + h];
            }

            float al = val ? (float)__builtin_bit_cast(f16, av) : 0.f;
            const f16x2* hp0 = (const f16x2*)&v0;
            const f16x2* hp1 = (const f16x2*)&v1;
            #pragma unroll
            for (int j = 0; j < 4; ++j) {
                f16x2 f = hp0[j];
                acc[2 * j + 0] = fmaf((float)f.x, al, acc[2 * j + 0]);
                acc[2 * j + 1] = fmaf((float)f.y, al, acc[2 * j + 1]);
            }
            #pragma unroll
            for (int j = 0; j < 4; ++j) {
                f16x2 f = hp1[j];
                acc[8 + 2 * j + 0] = fmaf((float)f.x, al, acc[8 + 2 * j + 0]);
                acc[8 + 2 * j + 1] = fmaf((float)f.y, al, acc[8 + 2 * j + 1]);
            }

            v0 = nv0; v1 = nv1; av = nav; val = val_n;
            p = pn;
        }
    }

    // cross-group reduce (lanes with same q across eidx groups hold same features)
    #pragma unroll
    for (int j = 0; j < 16; ++j) {
        acc[j] += __shfl_xor(acc[j], 16);
        acc[j] += __shfl_xor(acc[j], 32);
    }

    if (eidx == 0) {
        int4 o0, o1;
        f16x2* op0 = (f16x2*)&o0;
        f16x2* op1 = (f16x2*)&o1;
        #pragma unroll
        for (int j = 0; j < 4; ++j) {
            op0[j] = (f16x2){ (f16)acc[2 * j], (f16)acc[2 * j + 1] };
            op1[j] = (f16x2){ (f16)acc[8 + 2 * j], (f16)acc[8 + 2 * j + 1] };
        }
        int4* ar = (int4*)(agg + (size_t)n * HF + fb);
        ar[0] = o0; ar[1] = o1;
    }
}

// =====================================================================
// k_out_mlp2 (unchanged — verified round 4)
// =====================================================================
__global__ __launch_bounds__(256) void k_out_mlp2(
    const f16* __restrict__ agg,
    const float* __restrict__ Wf1, const float* __restrict__ bf1,
    const float* __restrict__ Wf2, const float* __restrict__ bf2,
    float* __restrict__ out)
{
    __shared__ __align__(16) f16 aggL[64][272];
    __shared__ __align__(16) f16 midL[64][72];

    const int t = threadIdx.x;
    const int base = blockIdx.x * 64;

    #pragma unroll
    for (int i = 0; i < 8; ++i) {
        int q = t + i * 256;
        int row = q >> 5, c8 = (q & 31) << 3;
        int gr = base + row; if (gr >= NN) gr = NN - 1;
        *(int4*)&aggL[row][c8] = *(const int4*)&agg[(size_t)gr * HF + c8];
    }
    __syncthreads();

    const int w = t >> 6, l = t & 63;
    const int g = l >> 4, c = l & 15;
    const f32x4 z4 = { 0.f, 0.f, 0.f, 0.f };

    {
        f32x4 acc[4] = { z4, z4, z4, z4 };
        for (int kc = 0; kc < 16; ++kc) {
            const float* wp = Wf1 + (size_t)(kc * 16 + 4 * g) * HI + w * 16 + c;
            f16x4 bf;
            bf[0] = (f16)wp[0]; bf[1] = (f16)wp[HI]; bf[2] = (f16)wp[2 * HI]; bf[3] = (f16)wp[3 * HI];
            #pragma unroll
            for (int m = 0; m < 4; ++m) {
                f16x4 af = *(const f16x4*)&aggL[m * 16 + c][kc * 16 + 4 * g];
                acc[m] = __builtin_amdgcn_mfma_f32_16x16x16f16(af, bf, acc[m], 0, 0, 0);
            }
        }
        float b = bf1[w * 16 + c];
        #pragma unroll
        for (int m = 0; m < 4; ++m)
            #pragma unroll
            for (int r = 0; r < 4; ++r)
                midL[m * 16 + 4 * g + r][w * 16 + c] = (f16)lrelu(acc[m][r] + b);
    }
    __syncthreads();

    #pragma unroll
    for (int nb = 0; nb < 2; ++nb) {
        int nt = w + nb * 4;
        f32x4 acc[4] = { z4, z4, z4, z4 };
        for (int kc = 0; kc < 4; ++kc) {
            const float* wp = Wf2 + (size_t)(kc * 16 + 4 * g) * OUT_DIM + nt * 16 + c;
            f16x4 bf;
            bf[0] = (f16)wp[0]; bf[1] = (f16)wp[OUT_DIM]; bf[2] = (f16)wp[2 * OUT_DIM]; bf[3] = (f16)wp[3 * OUT_DIM];
            #pragma unroll
            for (int m = 0; m < 4; ++m) {
                f16x4 af = *(const f16x4*)&midL[m * 16 + c][kc * 16 + 4 * g];
                acc[m] = __builtin_amdgcn_mfma_f32_16x16x16f16(af, bf, acc[m], 0, 0, 0);
            }
        }
        float b = bf2[nt * 16 + c];
        #pragma unroll
        for (int m = 0; m < 4; ++m)
            #pragma unroll
            for (int r = 0; r < 4; ++r) {
                int node = base + m * 16 + 4 * g + r;
                if (node < NN) out[(size_t)node * OUT_DIM + nt * 16 + c] = acc[m][r] + b;
            }
    }
}

extern "C" void kernel_launch(void* const* d_in, const int* in_sizes, int n_in,
                              void* d_out, int out_size, void* d_ws, size_t ws_size,
                              hipStream_t stream) {
    const float* x   = (const float*)d_in[0];
    const int*   ei  = (const int*)d_in[1];
    const float* Wi1 = (const float*)d_in[2];
    const float* bi1 = (const float*)d_in[3];
    const float* Wi2 = (const float*)d_in[4];
    const float* bi2 = (const float*)d_in[5];
    const float* Wa1 = (const float*)d_in[6];
    const float* ba1 = (const float*)d_in[7];
    const float* Wa2 = (const float*)d_in[8];
    const float* ba2 = (const float*)d_in[9];
    const float* Wf1 = (const float*)d_in[10];
    const float* bf1 = (const float*)d_in[11];
    const float* Wf2 = (const float*)d_in[12];
    const float* bf2 = (const float*)d_in[13];
    float* out = (float*)d_out;

    const size_t HS_B     = (size_t)NN * HF * sizeof(f16);           // 51.2e6
    const size_t OFF_SSRC = HS_B;
    const size_t OFF_SDST = 2 * HS_B;
    const size_t OFF_EATT = 3 * HS_B;
    const size_t OFF_ES2  = OFF_EATT + (size_t)NE * HEADS * sizeof(f16);
    const size_t OFF_CURS = OFF_ES2 + (size_t)NE * sizeof(int2);
    const size_t OFF_CURD = OFF_CURS + (size_t)NN * sizeof(int);
    const size_t OFF_BSUM = OFF_CURD + (size_t)NN * sizeof(int);
    const size_t NEED     = OFF_BSUM + 2 * NB_SCAN * sizeof(int);    // ~180.0 MB (<180.8 proven)
    if (ws_size < NEED) return;

    char* ws = (char*)d_ws;
    f16*  hs   = (f16*)(ws);
    f16*  ssrc = (f16*)(ws + OFF_SSRC);
    f16*  sdst = (f16*)(ws + OFF_SDST);
    f16*  eatt = (f16*)(ws + OFF_EATT);
    int2* es2  = (int2*)(ws + OFF_ES2);
    int*  cur_s = (int*)(ws + OFF_CURS);
    int*  cur_d = (int*)(ws + OFF_CURD);
    int*  bsum  = (int*)(ws + OFF_BSUM);
    f16*  agg  = (f16*)(ws + OFF_SSRC);       // aliases ssrc (dead after pass A)
    int2* ed2  = (int2*)(ws + OFF_SDST);      // aliases sdst (dead after pass A)

    const int NB64 = (NN + 63) / 64;

    k_embed<<<NB64, 256, 0, stream>>>(x, Wi1, bi1, Wi2, bi2, Wa1, hs, ssrc, sdst);

    (void)hipMemsetAsync(cur_s, 0, 2 * (size_t)NN * sizeof(int), stream);  // cur_s+cur_d contiguous
    k_deg2<<<NE / 256, 256, 0, stream>>>(ei, cur_s, cur_d);
    k_scan1<<<2 * NB_SCAN, 256, 0, stream>>>(cur_s, bsum);
    k_scan2<<<2, 256, 0, stream>>>(bsum);
    k_scan3<<<2 * NB_SCAN, 256, 0, stream>>>(cur_s, bsum);

    k_fill_src<<<NE / 256, 256, 0, stream>>>(ei, cur_s, es2);
    k_edge_att_csr<<<NN / 4, 256, 0, stream>>>(es2, cur_s, ssrc, sdst, ba1, Wa2, ba2, eatt, hs);

    k_fill_dst<<<NE / 256, 256, 0, stream>>>(ei, cur_d, ed2);
    k_aggregate_csr<<<NN / 4, 256, 0, stream>>>(ed2, cur_d, hs, eatt, agg);

    k_out_mlp2<<<NB64, 256, 0, stream>>>(agg, Wf1, bf1, Wf2, bf2, out);
}